// Round 6
// baseline (686.128 us; speedup 1.0000x reference)
//
#include <hip/hip_runtime.h>

typedef unsigned short u16;
typedef unsigned int   u32;
typedef __bf16   bf16x8 __attribute__((ext_vector_type(8)));
typedef float    f32x4  __attribute__((ext_vector_type(4)));
typedef u16      u16x4  __attribute__((ext_vector_type(4)));
typedef u16      u16x8  __attribute__((ext_vector_type(8)));
typedef u32      u32x2  __attribute__((ext_vector_type(2)));
typedef u32      u32x4  __attribute__((ext_vector_type(4)));

#if __has_builtin(__builtin_amdgcn_exp2f)
#define EXP2(x) __builtin_amdgcn_exp2f(x)
#else
#define EXP2(x) exp2f(x)
#endif

// fp32 -> bf16 round-to-nearest-even
__device__ __forceinline__ u16 f2bf(float f) {
    unsigned u = __float_as_uint(f);
    u += 0x7FFFu + ((u >> 16) & 1u);
    return (u16)(u >> 16);
}

__device__ __forceinline__ u32 pack_bf16(float a, float b) {
#if __has_builtin(__builtin_amdgcn_cvt_pk_bf16_f32)
    typedef __bf16 bf16x2 __attribute__((ext_vector_type(2)));
    bf16x2 r = __builtin_amdgcn_cvt_pk_bf16_f32(a, b);
    return __builtin_bit_cast(u32, r);
#else
    return (u32)f2bf(a) | ((u32)f2bf(b) << 16);
#endif
}

// async global->LDS, 16 bytes/lane. LDS dest = wave-uniform base + lane*16.
__device__ __forceinline__ void async_copy16(const u16* g, u16* l) {
    __builtin_amdgcn_global_load_lds(
        (const __attribute__((address_space(1))) unsigned*)g,
        (__attribute__((address_space(3))) unsigned*)l, 16, 0, 0);
}

__device__ __forceinline__ bf16x8 lds_frag(const u16* p) {
    return *(const bf16x8*)p;
}

// gfx950 cross-lane swaps (both operands read-write).
__device__ __forceinline__ void permlane32_swap(u32& a, u32& b) {
    asm("v_permlane32_swap_b32 %0, %1" : "+v"(a), "+v"(b));
}
__device__ __forceinline__ void permlane16_swap(u32& a, u32& b) {
    asm("v_permlane16_swap_b32 %0, %1" : "+v"(a), "+v"(b));
}

// ---------------------------------------------------------------------------
// Fused prep: blocks [0,768) transpose Wqkv, [768,1024) transpose Wout,
// [1024,5120) convert x to bf16 (16 elems/thread).
__global__ __launch_bounds__(256) void prep(const float* __restrict__ x,
                                            const float* __restrict__ Wqkv,
                                            const float* __restrict__ Wout,
                                            u16* __restrict__ xb,
                                            u16* __restrict__ wqkv_t,
                                            u16* __restrict__ wout_t) {
    __shared__ u16 t[64 * 72];
    const int bid = blockIdx.x;
    const int tid = threadIdx.x;

    if (bid >= 1024) {
        // x fp32 -> bf16
        size_t i = ((size_t)(bid - 1024) * 256 + tid) * 8;
        float4 v0 = *(const float4*)(x + i);
        float4 v1 = *(const float4*)(x + i + 4);
        u16x8 o = { f2bf(v0.x), f2bf(v0.y), f2bf(v0.z), f2bf(v0.w),
                    f2bf(v1.x), f2bf(v1.y), f2bf(v1.z), f2bf(v1.w) };
        *(u16x8*)(xb + i) = o;
        return;
    }

    // W fp32 [Kd][Nd] -> Wt bf16 [Nd][Kd]
    const float* W;  u16* Wt;  int Kd, Nd, n0, k0;
    if (bid < 768) { W = Wqkv; Wt = wqkv_t; Kd = 1024; Nd = 3072;
                     n0 = (bid % 48) * 64; k0 = (bid / 48) * 64; }
    else           { W = Wout; Wt = wout_t; Kd = 1024; Nd = 1024;
                     n0 = ((bid - 768) % 16) * 64; k0 = ((bid - 768) / 16) * 64; }
#pragma unroll
    for (int i = 0; i < 4; ++i) {
        int lin = i * 256 + tid;
        int kr = lin >> 4, nc = (lin & 15) << 2;
        float4 v = *(const float4*)(W + (size_t)(k0 + kr) * Nd + n0 + nc);
        u16x4 o = { f2bf(v.x), f2bf(v.y), f2bf(v.z), f2bf(v.w) };
        *(u16x4*)&t[kr * 72 + nc] = o;
    }
    __syncthreads();
#pragma unroll
    for (int i = 0; i < 2; ++i) {
        int lin = i * 256 + tid;
        int nr = lin >> 3, kc = (lin & 7) << 3;
        u16x8 o;
#pragma unroll
        for (int jj = 0; jj < 8; ++jj) o[jj] = t[(kc + jj) * 72 + nr];
        *(u16x8*)(Wt + (size_t)(n0 + nr) * Kd + k0 + kc) = o;
    }
}

// ---------------------------------------------------------------------------
// QKV gemm: C[M,N] = A[M,K] * Bt[N,K]^T, 128x128 tile, BK=32, double-buffered
// (one barrier/iter), LDS chunk-XOR swizzle (conflict-free). Proven structure
// (74.5 us, 690 TF). XCD/L2 region mapping (R5, FETCH 71.8->41 MB verified):
// 1536 blocks, region r = flat&7 covers a 16(by) x 12(bx) rectangle.
// Scatter epilogue: Q (scaled by 0.125*log2e) [bh][l][64], K [bh][l][64],
// V transposed [bh][kd][2048].
__global__ __launch_bounds__(256) void gemm_qkv(const u16* __restrict__ A,
                                                const u16* __restrict__ Bt,
                                                u16* __restrict__ outb,
                                                int K, int N) {
    __shared__ u16 As[2][128 * 32];
    __shared__ u16 Bs[2][128 * 32];
    const int tid = threadIdx.x;
    const int lane = tid & 63;
    const int wv = tid >> 6;
    const int wr = (wv >> 1) * 64;
    const int wc = (wv & 1) * 64;
    const int qd = lane >> 4;
    const int c  = lane & 15;

    // XCD/L2 region mapping (bijective over 1536 = 8 regions of 16x12 tiles)
    const int flat = blockIdx.x;
    const int r_ = flat & 7;
    const int q_ = flat >> 3;                 // 0..191
    const int m0 = ((r_ >> 1) * 16 + q_ / 12) * 128;
    const int n0 = ((r_ & 1) * 12 + q_ % 12) * 128;

    const int srow = tid >> 2;
    const int sg = ((tid & 3) ^ ((srow >> 1) & 3)) << 3;   // swizzled source chunk

    const u16* Ag0 = A  + (size_t)(m0 +      srow) * K + sg;
    const u16* Ag1 = A  + (size_t)(m0 + 64 + srow) * K + sg;
    const u16* Bg0 = Bt + (size_t)(n0 +      srow) * K + sg;
    const u16* Bg1 = Bt + (size_t)(n0 + 64 + srow) * K + sg;

    const u32 fsw = (qd ^ ((c >> 1) & 3)) << 3;            // swizzled frag chunk
    const u32 a_off = (wr + c) * 32 + fsw;                 // + i*512
    const u32 b_off = (wc + c) * 32 + fsw;                 // + j*512

    f32x4 acc[4][4] = {};

    async_copy16(Ag0, &As[0][tid * 8]);
    async_copy16(Ag1, &As[0][2048 + tid * 8]);
    async_copy16(Bg0, &Bs[0][tid * 8]);
    async_copy16(Bg1, &Bs[0][2048 + tid * 8]);

    int p = 0;
    for (int k0 = 0; k0 < K; k0 += 32) {
        __syncthreads();
        if (k0 + 32 < K) {
            const int np = p ^ 1;
            async_copy16(Ag0 + k0 + 32, &As[np][tid * 8]);
            async_copy16(Ag1 + k0 + 32, &As[np][2048 + tid * 8]);
            async_copy16(Bg0 + k0 + 32, &Bs[np][tid * 8]);
            async_copy16(Bg1 + k0 + 32, &Bs[np][2048 + tid * 8]);
        }
        bf16x8 af[4], bfr[4];
#pragma unroll
        for (int i = 0; i < 4; ++i) af[i]  = lds_frag(&As[p][a_off + i * 512]);
#pragma unroll
        for (int j = 0; j < 4; ++j) bfr[j] = lds_frag(&Bs[p][b_off + j * 512]);
#pragma unroll
        for (int i = 0; i < 4; ++i)
#pragma unroll
            for (int j = 0; j < 4; ++j)
                acc[i][j] = __builtin_amdgcn_mfma_f32_16x16x32_bf16(af[i], bfr[j], acc[i][j], 0, 0, 0);
        p ^= 1;
    }

    // C/D layout: col = lane&15, row = (lane>>4)*4 + reg
#pragma unroll
    for (int i = 0; i < 4; ++i)
#pragma unroll
        for (int j = 0; j < 4; ++j) {
            int n = n0 + wc + j * 16 + c;
            int which = n >> 10, h = (n >> 6) & 15, kd = n & 63;
            int m_base = m0 + wr + i * 16 + qd * 4;
            int b = m_base >> 11, l0 = m_base & 2047;
            int bh = b * 16 + h;
            if (which == 2) {
                u32x2 o2;
                o2[0] = pack_bf16(acc[i][j][0], acc[i][j][1]);
                o2[1] = pack_bf16(acc[i][j][2], acc[i][j][3]);
                *(u32x2*)(outb + (size_t)(128 + bh) * 131072 + (size_t)kd * 2048 + l0) = o2;
            } else if (which == 0) {
#pragma unroll
                for (int r = 0; r < 4; ++r)
                    outb[(size_t)bh * 131072 + (size_t)(l0 + r) * 64 + kd] =
                        f2bf(acc[i][j][r] * 0.1803368801f);   // 0.125*log2(e)
            } else {
#pragma unroll
                for (int r = 0; r < 4; ++r)
                    outb[(size_t)(64 + bh) * 131072 + (size_t)(l0 + r) * 64 + kd] =
                        f2bf(acc[i][j][r]);
            }
        }
}

// ---------------------------------------------------------------------------
// Output gemm: C[M,N] fp32 = A[M,K]bf16 * Bt[N,K]^T. 64x128 tile, BK=32,
// double-buffered, swizzled. 1024 blocks = 4 blocks/CU. XCD/L2 region
// mapping — region r = flat&7 covers 16 M-tiles x all 8 N-tiles.
__global__ __launch_bounds__(256) void gemm_out(const u16* __restrict__ A,
                                                const u16* __restrict__ Bt,
                                                float* __restrict__ outf,
                                                int K, int N) {
    __shared__ u16 As[2][64 * 32];
    __shared__ u16 Bs[2][128 * 32];
    const int tid = threadIdx.x;
    const int lane = tid & 63;
    const int wv = tid >> 6;
    const int wr = (wv >> 1) * 32;     // wave row-half: 0 or 32
    const int wc = (wv & 1) * 64;      // wave col-half: 0 or 64
    const int qd = lane >> 4;
    const int c  = lane & 15;

    const int flat = blockIdx.x + 8 * blockIdx.y;
    const int r_ = flat & 7;
    const int q_ = flat >> 3;                  // 0..127
    const int m0 = (r_ * 16 + (q_ >> 3)) * 64;
    const int n0 = (q_ & 7) * 128;

    const int srow = tid >> 2;         // 0..63
    const int sg = ((tid & 3) ^ ((srow >> 1) & 3)) << 3;

    const u16* Ag0 = A  + (size_t)(m0 +      srow) * K + sg;   // 64 rows, 1 issue
    const u16* Bg0 = Bt + (size_t)(n0 +      srow) * K + sg;
    const u16* Bg1 = Bt + (size_t)(n0 + 64 + srow) * K + sg;

    const u32 fsw = (qd ^ ((c >> 1) & 3)) << 3;
    const u32 a_off = (wr + c) * 32 + fsw;                 // + i*512
    const u32 b_off = (wc + c) * 32 + fsw;                 // + j*512

    f32x4 acc[2][4] = {};

    async_copy16(Ag0, &As[0][tid * 8]);
    async_copy16(Bg0, &Bs[0][tid * 8]);
    async_copy16(Bg1, &Bs[0][2048 + tid * 8]);

    int p = 0;
    for (int k0 = 0; k0 < K; k0 += 32) {
        __syncthreads();
        if (k0 + 32 < K) {
            const int np = p ^ 1;
            async_copy16(Ag0 + k0 + 32, &As[np][tid * 8]);
            async_copy16(Bg0 + k0 + 32, &Bs[np][tid * 8]);
            async_copy16(Bg1 + k0 + 32, &Bs[np][2048 + tid * 8]);
        }
        bf16x8 af[2], bfr[4];
#pragma unroll
        for (int i = 0; i < 2; ++i) af[i]  = lds_frag(&As[p][a_off + i * 512]);
#pragma unroll
        for (int j = 0; j < 4; ++j) bfr[j] = lds_frag(&Bs[p][b_off + j * 512]);
#pragma unroll
        for (int i = 0; i < 2; ++i)
#pragma unroll
            for (int j = 0; j < 4; ++j)
                acc[i][j] = __builtin_amdgcn_mfma_f32_16x16x32_bf16(af[i], bfr[j], acc[i][j], 0, 0, 0);
        p ^= 1;
    }

#pragma unroll
    for (int i = 0; i < 2; ++i)
#pragma unroll
        for (int j = 0; j < 4; ++j)
#pragma unroll
            for (int r = 0; r < 4; ++r) {
                int m = m0 + wr + i * 16 + qd * 4 + r;
                int n = n0 + wc + j * 16 + c;
                outf[(size_t)m * N + n] = acc[i][j][r];
            }
}

// ---------------------------------------------------------------------------
// Flash attention, causal, S^T form. Round-6 structure:
//  * R3's fused a/b streams (shared K and V fragment reads: 32 ds_read/tile)
//    PLUS the R1-style tile-level 2-deep pipeline, now with macro discipline
//    (no address-taken register arrays -- R1's scratch failure, fixed R2):
//      S(kt+1) MFMAs issued BEFORE finish(kt), so the exp2/permlane VALU of
//      tile kt executes under tile kt+1's in-flight S MFMAs.
//  * Two S register sets (A/B ping-pong via uniform kt&1 branch). Live S =
//    128 f32; VGPR ~210-235, no spill expected (watch WRITE_SIZE).
//  * V triple-buffered (finish(kt) lags the staging by one tile):
//    LDS = Ks 32K + Vt 48K = 80 KB -> still 2 blocks/CU.
//  * Barrier ledger: S(kt) reads Ks[kt&1] before iter-kt's barrier;
//    copy(kt+2) targets Ks[kt&1] + vFr, disjoint from vPV/vNx; rotation
//    vPV<-vNx<-vFr keeps finish(kt)'s V buffer intact.
#define ATTN_S_SET(KSB, SA, SB)                                               \
    do {                                                                      \
        _Pragma("unroll") for (int f = 0; f < 8; ++f) {                       \
            SA[f] = f32x4{-8.f, -8.f, -8.f, -8.f};                            \
            SB[f] = f32x4{-8.f, -8.f, -8.f, -8.f};                            \
        }                                                                     \
        __builtin_amdgcn_s_setprio(1);                                        \
        _Pragma("unroll") for (int ks = 0; ks < 2; ++ks) {                    \
            const u16* kp = (KSB) + kf_off[ks];                               \
            _Pragma("unroll") for (int f = 0; f < 8; ++f) {                   \
                bf16x8 kf = lds_frag(kp + f * 1024);                          \
                SA[f] = __builtin_amdgcn_mfma_f32_16x16x32_bf16(              \
                    kf, qa[ks], SA[f], 0, 0, 0);                              \
                SB[f] = __builtin_amdgcn_mfma_f32_16x16x32_bf16(              \
                    kf, qb[ks], SB[f], 0, 0, 0);                              \
            }                                                                 \
        }                                                                     \
        __builtin_amdgcn_s_setprio(0);                                        \
    } while (0)

#define ATTN_FINISH_SET(VTB, KT, SA, SB)                                      \
    do {                                                                      \
        if ((KT) == qt) {                                                     \
            _Pragma("unroll") for (int f = 0; f < 8; ++f)                     \
                _Pragma("unroll") for (int r = 0; r < 4; ++r) {               \
                    int key = (KT) * 128 + f * 16 + qd * 4 + r;               \
                    if (key > qa_row) SA[f][r] = -3e38f;                      \
                    if (key > qb_row) SB[f][r] = -3e38f;                      \
                }                                                             \
        }                                                                     \
        _Pragma("unroll") for (int f = 0; f < 8; ++f) {                       \
            _Pragma("unroll") for (int r = 0; r < 4; ++r) {                   \
                SA[f][r] = EXP2(SA[f][r]);                                    \
                SB[f][r] = EXP2(SB[f][r]);                                    \
            }                                                                 \
            rva += SA[f];                                                     \
            rvb += SB[f];                                                     \
        }                                                                     \
        _Pragma("unroll") for (int kc = 0; kc < 4; ++kc) {                    \
            u32 a0 = pack_bf16(SA[2 * kc][0], SA[2 * kc][1]);                 \
            u32 a1 = pack_bf16(SA[2 * kc + 1][0], SA[2 * kc + 1][1]);         \
            u32 b0 = pack_bf16(SA[2 * kc][2], SA[2 * kc][3]);                 \
            u32 b1 = pack_bf16(SA[2 * kc + 1][2], SA[2 * kc + 1][3]);         \
            permlane32_swap(a0, a1); permlane16_swap(a0, a1);                 \
            permlane32_swap(b0, b1); permlane16_swap(b0, b1);                 \
            u32x4 wpa = {a0, b0, a1, b1};                                     \
            bf16x8 pa = __builtin_bit_cast(bf16x8, wpa);                      \
            u32 c0 = pack_bf16(SB[2 * kc][0], SB[2 * kc][1]);                 \
            u32 c1 = pack_bf16(SB[2 * kc + 1][0], SB[2 * kc + 1][1]);         \
            u32 d0 = pack_bf16(SB[2 * kc][2], SB[2 * kc][3]);                 \
            u32 d1 = pack_bf16(SB[2 * kc + 1][2], SB[2 * kc + 1][3]);         \
            permlane32_swap(c0, c1); permlane16_swap(c0, c1);                 \
            permlane32_swap(d0, d1); permlane16_swap(d0, d1);                 \
            u32x4 wpb = {c0, d0, c1, d1};                                     \
            bf16x8 pb = __builtin_bit_cast(bf16x8, wpb);                      \
            const u16* vp = (VTB) + vf_off[kc];                               \
            __builtin_amdgcn_s_setprio(1);                                    \
            _Pragma("unroll") for (int jo = 0; jo < 4; ++jo) {                \
                bf16x8 vf = lds_frag(vp + jo * 2048);                         \
                acca[jo] = __builtin_amdgcn_mfma_f32_16x16x32_bf16(           \
                    vf, pa, acca[jo], 0, 0, 0);                               \
                accb[jo] = __builtin_amdgcn_mfma_f32_16x16x32_bf16(           \
                    vf, pb, accb[jo], 0, 0, 0);                               \
            }                                                                 \
            __builtin_amdgcn_s_setprio(0);                                    \
        }                                                                     \
    } while (0)

__global__ __launch_bounds__(256, 2) void attn_kernel(const u16* __restrict__ qkv,
                                                      u16* __restrict__ att) {
    __shared__ u16 Ks[2][128 * 64];   // [key][kd], 16B-chunk XOR swizzled
    __shared__ u16 Vt[3][64 * 128];   // [kd][key], 16B-chunk XOR swizzled

    const int tid = threadIdx.x;
    const int lane = tid & 63;
    const int w = tid >> 6;
    const int qd = lane >> 4;
    const int c = lane & 15;

    // XCD swizzle: flat%8 == bh%8 -> one bh's K/V stays in one XCD L2
    const int flat = blockIdx.x + 8 * blockIdx.y;
    const int bh = (flat & 7) + 8 * ((flat >> 3) & 7);
    const int bx = flat >> 6;
    const int b = bh >> 4, h = bh & 15;

    const u16* Qg = qkv + (size_t)bh * 131072;
    const u16* Kg = qkv + (size_t)(64 + bh) * 131072;
    const u16* Vg = qkv + (size_t)(128 + bh) * 131072;   // [kd][2048]

    u32 kf_off[2];
#pragma unroll
    for (int ks = 0; ks < 2; ++ks)
        kf_off[ks] = c * 64 + (((ks * 4 + qd) ^ (c & 7)) << 3);
    u32 vf_off[4];
#pragma unroll
    for (int kc = 0; kc < 4; ++kc)
        vf_off[kc] = c * 128 + (((kc * 4 + qd) ^ c) << 3);

    // 8 x 16B async copies per tile (K and V), pre-swizzled global source,
    // linear LDS dest (global_load_lds requirement). Writes LDS only.
    auto issue_copy = [&](int t, u16* kd, u16* vd) {
#pragma unroll
        for (int it = 0; it < 4; ++it) {
            int lin = it * 256 + tid;
            int krw = lin >> 3, kch = lin & 7;
            int vrw = lin >> 4, vch = lin & 15;
            async_copy16(Kg + (size_t)t * 8192 + krw * 64 + ((kch ^ (krw & 7)) << 3),
                         kd + lin * 8);
            async_copy16(Vg + (size_t)t * 128 + (size_t)vrw * 2048 + ((vch ^ (vrw & 15)) << 3),
                         vd + lin * 8);
        }
    };

#pragma unroll 1
    for (int seg = 0; seg < 2; ++seg) {
        const int qt = seg ? (15 - bx) : bx;            // balanced causal pairing
        const int qa_row = qt * 128 + w * 32 + c;       // frag a
        const int qb_row = qa_row + 16;                 // frag b

        bf16x8 qa[2], qb[2];
#pragma unroll
        for (int ks = 0; ks < 2; ++ks) {
            qa[ks] = *(const bf16x8*)(Qg + (size_t)qa_row * 64 + ks * 32 + qd * 8);
            qb[ks] = *(const bf16x8*)(Qg + (size_t)qb_row * 64 + ks * 32 + qd * 8);
        }

        f32x4 acca[4] = {}, accb[4] = {};
        f32x4 rva = {}, rvb = {};                        // packed row-sum accum
        f32x4 saA[8], sbA[8], saB[8], sbB[8];            // two S sets (ping-pong)

        const int nkt = qt + 1;

        // ---- prologue: tile 0 staged; tile 1 issued; S(0) -> set A ----
        __syncthreads();                     // prev-seg readers done with bufs
        issue_copy(0, Ks[0], Vt[0]);
        __syncthreads();                     // tile 0 landed (all waves)
        if (nkt > 1) issue_copy(1, Ks[1], Vt[1]);
        ATTN_S_SET(Ks[0], saA, sbA);

        u16 *vPV = Vt[0], *vNx = Vt[1], *vFr = Vt[2];

#pragma unroll 1
        for (int kt = 0; kt < nkt; ++kt) {
            if ((kt & 1) == 0) {
                if (kt + 1 < nkt) {
                    __syncthreads();                         // tile kt+1 landed
                    if (kt + 2 < nkt) issue_copy(kt + 2, Ks[kt & 1], vFr);
                    ATTN_S_SET(Ks[(kt + 1) & 1], saB, sbB);  // S(kt+1) in flight
                }
                ATTN_FINISH_SET(vPV, kt, saA, sbA);          // VALU under MFMAs
            } else {
                if (kt + 1 < nkt) {
                    __syncthreads();
                    if (kt + 2 < nkt) issue_copy(kt + 2, Ks[kt & 1], vFr);
                    ATTN_S_SET(Ks[(kt + 1) & 1], saA, sbA);
                }
                ATTN_FINISH_SET(vPV, kt, saB, sbB);
            }
            u16* t0 = vPV; vPV = vNx; vNx = vFr; vFr = t0;
        }

        // epilogue: reduce row-sums across the 4 quad-groups, then scale
        float ra = rva[0] + rva[1] + rva[2] + rva[3];
        float rb = rvb[0] + rvb[1] + rvb[2] + rvb[3];
        ra += __shfl_xor(ra, 16, 64);
        ra += __shfl_xor(ra, 32, 64);
        rb += __shfl_xor(rb, 16, 64);
        rb += __shfl_xor(rb, 32, 64);
        float ia = __builtin_amdgcn_rcpf(ra), ib = __builtin_amdgcn_rcpf(rb);
        u16* ar = att + ((size_t)b * 2048 + qa_row) * 1024 + h * 64;
        u16* br = att + ((size_t)b * 2048 + qb_row) * 1024 + h * 64;
#pragma unroll
        for (int jo = 0; jo < 4; ++jo) {
            u32x2 oa, ob;
            oa[0] = pack_bf16(acca[jo][0] * ia, acca[jo][1] * ia);
            oa[1] = pack_bf16(acca[jo][2] * ia, acca[jo][3] * ia);
            ob[0] = pack_bf16(accb[jo][0] * ib, accb[jo][1] * ib);
            ob[1] = pack_bf16(accb[jo][2] * ib, accb[jo][3] * ib);
            *(u32x2*)(ar + jo * 16 + qd * 4) = oa;
            *(u32x2*)(br + jo * 16 + qd * 4) = ob;
        }
    }
}

// ---------------------------------------------------------------------------
extern "C" void kernel_launch(void* const* d_in, const int* in_sizes, int n_in,
                              void* d_out, int out_size, void* d_ws, size_t ws_size,
                              hipStream_t stream) {
    const float* x    = (const float*)d_in[0];   // [4,2048,1024]
    const float* Wqkv = (const float*)d_in[1];   // [1024,3072]
    const float* Wout = (const float*)d_in[2];   // [1024,1024]
    float* out = (float*)d_out;                  // [4,2048,1024] fp32

    char* ws = (char*)d_ws;
    u16* x_bf   = (u16*)(ws);                    // 16 MB
    u16* wqkv_t = (u16*)(ws + 16777216);         // 6 MB   [3072][1024]
    u16* wout_t = (u16*)(ws + 23068672);         // 2 MB   [1024][1024]
    u16* qkv_h  = (u16*)(ws + 25165824);         // 48 MB  Q,K [bh][l][64], V^T [bh][kd][2048]
    u16* att    = (u16*)(ws + 75497472);         // 16 MB  [4][2048][1024]

    prep<<<dim3(5120), dim3(256), 0, stream>>>(x, Wqkv, Wout, x_bf, wqkv_t, wout_t);
    gemm_qkv<<<dim3(1536), dim3(256), 0, stream>>>(x_bf, wqkv_t, qkv_h, 1024, 3072);
    attn_kernel<<<dim3(8, 64), dim3(256), 0, stream>>>(qkv_h, att);
    gemm_out<<<dim3(8, 128), dim3(256), 0, stream>>>(att, wout_t, out, 1024, 1024);
}

// Round 7
// 245.167 us; speedup vs baseline: 2.7986x; 2.7986x over previous
//
#include <hip/hip_runtime.h>

typedef unsigned short u16;
typedef unsigned int   u32;
typedef __bf16   bf16x8 __attribute__((ext_vector_type(8)));
typedef float    f32x4  __attribute__((ext_vector_type(4)));
typedef u16      u16x4  __attribute__((ext_vector_type(4)));
typedef u16      u16x8  __attribute__((ext_vector_type(8)));
typedef u32      u32x2  __attribute__((ext_vector_type(2)));
typedef u32      u32x4  __attribute__((ext_vector_type(4)));

#if __has_builtin(__builtin_amdgcn_exp2f)
#define EXP2(x) __builtin_amdgcn_exp2f(x)
#else
#define EXP2(x) exp2f(x)
#endif

// fp32 -> bf16 round-to-nearest-even
__device__ __forceinline__ u16 f2bf(float f) {
    unsigned u = __float_as_uint(f);
    u += 0x7FFFu + ((u >> 16) & 1u);
    return (u16)(u >> 16);
}

__device__ __forceinline__ u32 pack_bf16(float a, float b) {
#if __has_builtin(__builtin_amdgcn_cvt_pk_bf16_f32)
    typedef __bf16 bf16x2 __attribute__((ext_vector_type(2)));
    bf16x2 r = __builtin_amdgcn_cvt_pk_bf16_f32(a, b);
    return __builtin_bit_cast(u32, r);
#else
    return (u32)f2bf(a) | ((u32)f2bf(b) << 16);
#endif
}

// async global->LDS, 16 bytes/lane. LDS dest = wave-uniform base + lane*16.
__device__ __forceinline__ void async_copy16(const u16* g, u16* l) {
    __builtin_amdgcn_global_load_lds(
        (const __attribute__((address_space(1))) unsigned*)g,
        (__attribute__((address_space(3))) unsigned*)l, 16, 0, 0);
}

__device__ __forceinline__ bf16x8 lds_frag(const u16* p) {
    return *(const bf16x8*)p;
}

// gfx950 cross-lane swaps (both operands read-write).
__device__ __forceinline__ void permlane32_swap(u32& a, u32& b) {
    asm("v_permlane32_swap_b32 %0, %1" : "+v"(a), "+v"(b));
}
__device__ __forceinline__ void permlane16_swap(u32& a, u32& b) {
    asm("v_permlane16_swap_b32 %0, %1" : "+v"(a), "+v"(b));
}

// ---------------------------------------------------------------------------
// Fused prep: blocks [0,768) transpose Wqkv, [768,1024) transpose Wout,
// [1024,5120) convert x to bf16 (16 elems/thread).
__global__ __launch_bounds__(256) void prep(const float* __restrict__ x,
                                            const float* __restrict__ Wqkv,
                                            const float* __restrict__ Wout,
                                            u16* __restrict__ xb,
                                            u16* __restrict__ wqkv_t,
                                            u16* __restrict__ wout_t) {
    __shared__ u16 t[64 * 72];
    const int bid = blockIdx.x;
    const int tid = threadIdx.x;

    if (bid >= 1024) {
        // x fp32 -> bf16
        size_t i = ((size_t)(bid - 1024) * 256 + tid) * 8;
        float4 v0 = *(const float4*)(x + i);
        float4 v1 = *(const float4*)(x + i + 4);
        u16x8 o = { f2bf(v0.x), f2bf(v0.y), f2bf(v0.z), f2bf(v0.w),
                    f2bf(v1.x), f2bf(v1.y), f2bf(v1.z), f2bf(v1.w) };
        *(u16x8*)(xb + i) = o;
        return;
    }

    // W fp32 [Kd][Nd] -> Wt bf16 [Nd][Kd]
    const float* W;  u16* Wt;  int Kd, Nd, n0, k0;
    if (bid < 768) { W = Wqkv; Wt = wqkv_t; Kd = 1024; Nd = 3072;
                     n0 = (bid % 48) * 64; k0 = (bid / 48) * 64; }
    else           { W = Wout; Wt = wout_t; Kd = 1024; Nd = 1024;
                     n0 = ((bid - 768) % 16) * 64; k0 = ((bid - 768) / 16) * 64; }
#pragma unroll
    for (int i = 0; i < 4; ++i) {
        int lin = i * 256 + tid;
        int kr = lin >> 4, nc = (lin & 15) << 2;
        float4 v = *(const float4*)(W + (size_t)(k0 + kr) * Nd + n0 + nc);
        u16x4 o = { f2bf(v.x), f2bf(v.y), f2bf(v.z), f2bf(v.w) };
        *(u16x4*)&t[kr * 72 + nc] = o;
    }
    __syncthreads();
#pragma unroll
    for (int i = 0; i < 2; ++i) {
        int lin = i * 256 + tid;
        int nr = lin >> 3, kc = (lin & 7) << 3;
        u16x8 o;
#pragma unroll
        for (int jj = 0; jj < 8; ++jj) o[jj] = t[(kc + jj) * 72 + nr];
        *(u16x8*)(Wt + (size_t)(n0 + nr) * Kd + k0 + kc) = o;
    }
}

// ---------------------------------------------------------------------------
// QKV gemm: C[M,N] = A[M,K] * Bt[N,K]^T, 128x128 tile, BK=32, double-buffered
// (one barrier/iter), LDS chunk-XOR swizzle (conflict-free). Proven structure
// (74.5 us, 690 TF). XCD/L2 region mapping (R5, FETCH 71.8->41 MB verified):
// 1536 blocks, region r = flat&7 covers a 16(by) x 12(bx) rectangle.
// NOTE do-not-retry list: (a) coarse 8-phase 256^2 port (R4: -27%, occupancy
// halved, m196-coarse variant); (b) attn tile-level 2-deep S pipeline
// (R1/R6: register state > budget -> scratch spill, 2 GB traffic).
// Scatter epilogue: Q (scaled by 0.125*log2e) [bh][l][64], K [bh][l][64],
// V transposed [bh][kd][2048].
__global__ __launch_bounds__(256) void gemm_qkv(const u16* __restrict__ A,
                                                const u16* __restrict__ Bt,
                                                u16* __restrict__ outb,
                                                int K, int N) {
    __shared__ u16 As[2][128 * 32];
    __shared__ u16 Bs[2][128 * 32];
    const int tid = threadIdx.x;
    const int lane = tid & 63;
    const int wv = tid >> 6;
    const int wr = (wv >> 1) * 64;
    const int wc = (wv & 1) * 64;
    const int qd = lane >> 4;
    const int c  = lane & 15;

    // XCD/L2 region mapping (bijective over 1536 = 8 regions of 16x12 tiles)
    const int flat = blockIdx.x;
    const int r_ = flat & 7;
    const int q_ = flat >> 3;                 // 0..191
    const int m0 = ((r_ >> 1) * 16 + q_ / 12) * 128;
    const int n0 = ((r_ & 1) * 12 + q_ % 12) * 128;

    const int srow = tid >> 2;
    const int sg = ((tid & 3) ^ ((srow >> 1) & 3)) << 3;   // swizzled source chunk

    const u16* Ag0 = A  + (size_t)(m0 +      srow) * K + sg;
    const u16* Ag1 = A  + (size_t)(m0 + 64 + srow) * K + sg;
    const u16* Bg0 = Bt + (size_t)(n0 +      srow) * K + sg;
    const u16* Bg1 = Bt + (size_t)(n0 + 64 + srow) * K + sg;

    const u32 fsw = (qd ^ ((c >> 1) & 3)) << 3;            // swizzled frag chunk
    const u32 a_off = (wr + c) * 32 + fsw;                 // + i*512
    const u32 b_off = (wc + c) * 32 + fsw;                 // + j*512

    f32x4 acc[4][4] = {};

    async_copy16(Ag0, &As[0][tid * 8]);
    async_copy16(Ag1, &As[0][2048 + tid * 8]);
    async_copy16(Bg0, &Bs[0][tid * 8]);
    async_copy16(Bg1, &Bs[0][2048 + tid * 8]);

    int p = 0;
    for (int k0 = 0; k0 < K; k0 += 32) {
        __syncthreads();
        if (k0 + 32 < K) {
            const int np = p ^ 1;
            async_copy16(Ag0 + k0 + 32, &As[np][tid * 8]);
            async_copy16(Ag1 + k0 + 32, &As[np][2048 + tid * 8]);
            async_copy16(Bg0 + k0 + 32, &Bs[np][tid * 8]);
            async_copy16(Bg1 + k0 + 32, &Bs[np][2048 + tid * 8]);
        }
        bf16x8 af[4], bfr[4];
#pragma unroll
        for (int i = 0; i < 4; ++i) af[i]  = lds_frag(&As[p][a_off + i * 512]);
#pragma unroll
        for (int j = 0; j < 4; ++j) bfr[j] = lds_frag(&Bs[p][b_off + j * 512]);
#pragma unroll
        for (int i = 0; i < 4; ++i)
#pragma unroll
            for (int j = 0; j < 4; ++j)
                acc[i][j] = __builtin_amdgcn_mfma_f32_16x16x32_bf16(af[i], bfr[j], acc[i][j], 0, 0, 0);
        p ^= 1;
    }

    // C/D layout: col = lane&15, row = (lane>>4)*4 + reg
#pragma unroll
    for (int i = 0; i < 4; ++i)
#pragma unroll
        for (int j = 0; j < 4; ++j) {
            int n = n0 + wc + j * 16 + c;
            int which = n >> 10, h = (n >> 6) & 15, kd = n & 63;
            int m_base = m0 + wr + i * 16 + qd * 4;
            int b = m_base >> 11, l0 = m_base & 2047;
            int bh = b * 16 + h;
            if (which == 2) {
                u32x2 o2;
                o2[0] = pack_bf16(acc[i][j][0], acc[i][j][1]);
                o2[1] = pack_bf16(acc[i][j][2], acc[i][j][3]);
                *(u32x2*)(outb + (size_t)(128 + bh) * 131072 + (size_t)kd * 2048 + l0) = o2;
            } else if (which == 0) {
#pragma unroll
                for (int r = 0; r < 4; ++r)
                    outb[(size_t)bh * 131072 + (size_t)(l0 + r) * 64 + kd] =
                        f2bf(acc[i][j][r] * 0.1803368801f);   // 0.125*log2(e)
            } else {
#pragma unroll
                for (int r = 0; r < 4; ++r)
                    outb[(size_t)(64 + bh) * 131072 + (size_t)(l0 + r) * 64 + kd] =
                        f2bf(acc[i][j][r]);
            }
        }
}

// ---------------------------------------------------------------------------
// Output gemm: C[M,N] fp32 = A[M,K]bf16 * Bt[N,K]^T. 64x128 tile, BK=32,
// double-buffered, swizzled. 1024 blocks = 4 blocks/CU. XCD/L2 region
// mapping — region r = flat&7 covers 16 M-tiles x all 8 N-tiles.
__global__ __launch_bounds__(256) void gemm_out(const u16* __restrict__ A,
                                                const u16* __restrict__ Bt,
                                                float* __restrict__ outf,
                                                int K, int N) {
    __shared__ u16 As[2][64 * 32];
    __shared__ u16 Bs[2][128 * 32];
    const int tid = threadIdx.x;
    const int lane = tid & 63;
    const int wv = tid >> 6;
    const int wr = (wv >> 1) * 32;     // wave row-half: 0 or 32
    const int wc = (wv & 1) * 64;      // wave col-half: 0 or 64
    const int qd = lane >> 4;
    const int c  = lane & 15;

    const int flat = blockIdx.x + 8 * blockIdx.y;
    const int r_ = flat & 7;
    const int q_ = flat >> 3;                  // 0..127
    const int m0 = (r_ * 16 + (q_ >> 3)) * 64;
    const int n0 = (q_ & 7) * 128;

    const int srow = tid >> 2;         // 0..63
    const int sg = ((tid & 3) ^ ((srow >> 1) & 3)) << 3;

    const u16* Ag0 = A  + (size_t)(m0 +      srow) * K + sg;   // 64 rows, 1 issue
    const u16* Bg0 = Bt + (size_t)(n0 +      srow) * K + sg;
    const u16* Bg1 = Bt + (size_t)(n0 + 64 + srow) * K + sg;

    const u32 fsw = (qd ^ ((c >> 1) & 3)) << 3;
    const u32 a_off = (wr + c) * 32 + fsw;                 // + i*512
    const u32 b_off = (wc + c) * 32 + fsw;                 // + j*512

    f32x4 acc[2][4] = {};

    async_copy16(Ag0, &As[0][tid * 8]);
    async_copy16(Bg0, &Bs[0][tid * 8]);
    async_copy16(Bg1, &Bs[0][2048 + tid * 8]);

    int p = 0;
    for (int k0 = 0; k0 < K; k0 += 32) {
        __syncthreads();
        if (k0 + 32 < K) {
            const int np = p ^ 1;
            async_copy16(Ag0 + k0 + 32, &As[np][tid * 8]);
            async_copy16(Bg0 + k0 + 32, &Bs[np][tid * 8]);
            async_copy16(Bg1 + k0 + 32, &Bs[np][2048 + tid * 8]);
        }
        bf16x8 af[2], bfr[4];
#pragma unroll
        for (int i = 0; i < 2; ++i) af[i]  = lds_frag(&As[p][a_off + i * 512]);
#pragma unroll
        for (int j = 0; j < 4; ++j) bfr[j] = lds_frag(&Bs[p][b_off + j * 512]);
#pragma unroll
        for (int i = 0; i < 2; ++i)
#pragma unroll
            for (int j = 0; j < 4; ++j)
                acc[i][j] = __builtin_amdgcn_mfma_f32_16x16x32_bf16(af[i], bfr[j], acc[i][j], 0, 0, 0);
        p ^= 1;
    }

#pragma unroll
    for (int i = 0; i < 2; ++i)
#pragma unroll
        for (int j = 0; j < 4; ++j)
#pragma unroll
            for (int r = 0; r < 4; ++r) {
                int m = m0 + wr + i * 16 + qd * 4 + r;
                int n = n0 + wc + j * 16 + c;
                outf[(size_t)m * N + n] = acc[i][j][r];
            }
}

// ---------------------------------------------------------------------------
// Flash attention, causal, S^T form (round-3 fused-stream version, verified:
// ~73 us, WRITE ~20.5 MB, no scratch). Fused a/b streams: each K fragment
// read feeds BOTH sa and sb MFMAs; each V fragment read feeds acca and accb
// (32 ds_read/tile). In-register P^T via v_permlane{32,16}_swap, exp2 bias
// -8 folded into MFMA C-init, packed f32x4 row-sums, setprio on MFMA
// clusters, K/V double-buffered (64 KB -> 2 blocks/CU), one barrier/tile.
#define ATTN_S_AB(KSB)                                                        \
    do {                                                                      \
        _Pragma("unroll") for (int f = 0; f < 8; ++f) {                       \
            sa[f] = f32x4{-8.f, -8.f, -8.f, -8.f};                            \
            sb[f] = f32x4{-8.f, -8.f, -8.f, -8.f};                            \
        }                                                                     \
        __builtin_amdgcn_s_setprio(1);                                        \
        _Pragma("unroll") for (int ks = 0; ks < 2; ++ks) {                    \
            const u16* kp = (KSB) + kf_off[ks];                               \
            _Pragma("unroll") for (int f = 0; f < 8; ++f) {                   \
                bf16x8 kf = lds_frag(kp + f * 1024);                          \
                sa[f] = __builtin_amdgcn_mfma_f32_16x16x32_bf16(              \
                    kf, qa[ks], sa[f], 0, 0, 0);                              \
                sb[f] = __builtin_amdgcn_mfma_f32_16x16x32_bf16(              \
                    kf, qb[ks], sb[f], 0, 0, 0);                              \
            }                                                                 \
        }                                                                     \
        __builtin_amdgcn_s_setprio(0);                                        \
    } while (0)

#define ATTN_FINISH_AB(VTB, KT)                                               \
    do {                                                                      \
        if ((KT) == qt) {                                                     \
            _Pragma("unroll") for (int f = 0; f < 8; ++f)                     \
                _Pragma("unroll") for (int r = 0; r < 4; ++r) {               \
                    int key = (KT) * 128 + f * 16 + qd * 4 + r;               \
                    if (key > qa_row) sa[f][r] = -3e38f;                      \
                    if (key > qb_row) sb[f][r] = -3e38f;                      \
                }                                                             \
        }                                                                     \
        _Pragma("unroll") for (int f = 0; f < 8; ++f) {                       \
            _Pragma("unroll") for (int r = 0; r < 4; ++r) {                   \
                sa[f][r] = EXP2(sa[f][r]);                                    \
                sb[f][r] = EXP2(sb[f][r]);                                    \
            }                                                                 \
            rva += sa[f];                                                     \
            rvb += sb[f];                                                     \
        }                                                                     \
        _Pragma("unroll") for (int kc = 0; kc < 4; ++kc) {                    \
            u32 a0 = pack_bf16(sa[2 * kc][0], sa[2 * kc][1]);                 \
            u32 a1 = pack_bf16(sa[2 * kc + 1][0], sa[2 * kc + 1][1]);         \
            u32 b0 = pack_bf16(sa[2 * kc][2], sa[2 * kc][3]);                 \
            u32 b1 = pack_bf16(sa[2 * kc + 1][2], sa[2 * kc + 1][3]);         \
            permlane32_swap(a0, a1); permlane16_swap(a0, a1);                 \
            permlane32_swap(b0, b1); permlane16_swap(b0, b1);                 \
            u32x4 wpa = {a0, b0, a1, b1};                                     \
            bf16x8 pa = __builtin_bit_cast(bf16x8, wpa);                      \
            u32 c0 = pack_bf16(sb[2 * kc][0], sb[2 * kc][1]);                 \
            u32 c1 = pack_bf16(sb[2 * kc + 1][0], sb[2 * kc + 1][1]);         \
            u32 d0 = pack_bf16(sb[2 * kc][2], sb[2 * kc][3]);                 \
            u32 d1 = pack_bf16(sb[2 * kc + 1][2], sb[2 * kc + 1][3]);         \
            permlane32_swap(c0, c1); permlane16_swap(c0, c1);                 \
            permlane32_swap(d0, d1); permlane16_swap(d0, d1);                 \
            u32x4 wpb = {c0, d0, c1, d1};                                     \
            bf16x8 pb = __builtin_bit_cast(bf16x8, wpb);                      \
            const u16* vp = (VTB) + vf_off[kc];                               \
            __builtin_amdgcn_s_setprio(1);                                    \
            _Pragma("unroll") for (int jo = 0; jo < 4; ++jo) {                \
                bf16x8 vf = lds_frag(vp + jo * 2048);                         \
                acca[jo] = __builtin_amdgcn_mfma_f32_16x16x32_bf16(           \
                    vf, pa, acca[jo], 0, 0, 0);                               \
                accb[jo] = __builtin_amdgcn_mfma_f32_16x16x32_bf16(           \
                    vf, pb, accb[jo], 0, 0, 0);                               \
            }                                                                 \
            __builtin_amdgcn_s_setprio(0);                                    \
        }                                                                     \
    } while (0)

__global__ __launch_bounds__(256, 2) void attn_kernel(const u16* __restrict__ qkv,
                                                      u16* __restrict__ att) {
    __shared__ u16 Ks[2][128 * 64];   // [key][kd], 16B-chunk XOR swizzled
    __shared__ u16 Vt[2][64 * 128];   // [kd][key], 16B-chunk XOR swizzled

    const int tid = threadIdx.x;
    const int lane = tid & 63;
    const int w = tid >> 6;
    const int qd = lane >> 4;
    const int c = lane & 15;

    // XCD swizzle: flat%8 == bh%8 -> one bh's K/V stays in one XCD L2
    const int flat = blockIdx.x + 8 * blockIdx.y;
    const int bh = (flat & 7) + 8 * ((flat >> 3) & 7);
    const int bx = flat >> 6;
    const int b = bh >> 4, h = bh & 15;

    const u16* Qg = qkv + (size_t)bh * 131072;
    const u16* Kg = qkv + (size_t)(64 + bh) * 131072;
    const u16* Vg = qkv + (size_t)(128 + bh) * 131072;   // [kd][2048]

    u32 kf_off[2];
#pragma unroll
    for (int ks = 0; ks < 2; ++ks)
        kf_off[ks] = c * 64 + (((ks * 4 + qd) ^ (c & 7)) << 3);
    u32 vf_off[4];
#pragma unroll
    for (int kc = 0; kc < 4; ++kc)
        vf_off[kc] = c * 128 + (((kc * 4 + qd) ^ c) << 3);

    // 8 x 16B async copies per tile (K and V), pre-swizzled global source,
    // linear LDS dest (global_load_lds requirement). Writes LDS only.
    auto issue_copy = [&](int t, u16* kd, u16* vd) {
#pragma unroll
        for (int it = 0; it < 4; ++it) {
            int lin = it * 256 + tid;
            int krw = lin >> 3, kch = lin & 7;
            int vrw = lin >> 4, vch = lin & 15;
            async_copy16(Kg + (size_t)t * 8192 + krw * 64 + ((kch ^ (krw & 7)) << 3),
                         kd + lin * 8);
            async_copy16(Vg + (size_t)t * 128 + (size_t)vrw * 2048 + ((vch ^ (vrw & 15)) << 3),
                         vd + lin * 8);
        }
    };

#pragma unroll 1
    for (int seg = 0; seg < 2; ++seg) {
        const int qt = seg ? (15 - bx) : bx;            // balanced causal pairing
        const int qa_row = qt * 128 + w * 32 + c;       // frag a
        const int qb_row = qa_row + 16;                 // frag b

        bf16x8 qa[2], qb[2];
#pragma unroll
        for (int ks = 0; ks < 2; ++ks) {
            qa[ks] = *(const bf16x8*)(Qg + (size_t)qa_row * 64 + ks * 32 + qd * 8);
            qb[ks] = *(const bf16x8*)(Qg + (size_t)qb_row * 64 + ks * 32 + qd * 8);
        }

        f32x4 acca[4] = {}, accb[4] = {};
        f32x4 rva = {}, rvb = {};                        // packed row-sum accum
        f32x4 sa[8], sb[8];

        const int nkt = qt + 1;

        // ---- prologue: tile 0 staged; tile 1 issued ----
        __syncthreads();                     // prev-seg readers done with bufs
        issue_copy(0, Ks[0], Vt[0]);
        __syncthreads();                     // tile 0 landed (all waves)
        if (nkt > 1) issue_copy(1, Ks[1], Vt[1]);

#pragma unroll 1
        for (int kt = 0; kt < nkt; ++kt) {
            const int p = kt & 1;
            ATTN_S_AB(Ks[p]);                // 32 MFMA, 16 shared kf reads
            ATTN_FINISH_AB(Vt[p], kt);       // exp2/permlane + 32 MFMA, 16 vf reads
            if (kt + 1 < nkt) {
                __syncthreads();             // tile kt+1 landed; buf p free
                if (kt + 2 < nkt) issue_copy(kt + 2, Ks[p], Vt[p]);
            }
        }

        // epilogue: reduce row-sums across the 4 quad-groups, then scale
        float ra = rva[0] + rva[1] + rva[2] + rva[3];
        float rb = rvb[0] + rvb[1] + rvb[2] + rvb[3];
        ra += __shfl_xor(ra, 16, 64);
        ra += __shfl_xor(ra, 32, 64);
        rb += __shfl_xor(rb, 16, 64);
        rb += __shfl_xor(rb, 32, 64);
        float ia = __builtin_amdgcn_rcpf(ra), ib = __builtin_amdgcn_rcpf(rb);
        u16* ar = att + ((size_t)b * 2048 + qa_row) * 1024 + h * 64;
        u16* br = att + ((size_t)b * 2048 + qb_row) * 1024 + h * 64;
#pragma unroll
        for (int jo = 0; jo < 4; ++jo) {
            u32x2 oa, ob;
            oa[0] = pack_bf16(acca[jo][0] * ia, acca[jo][1] * ia);
            oa[1] = pack_bf16(acca[jo][2] * ia, acca[jo][3] * ia);
            ob[0] = pack_bf16(accb[jo][0] * ib, accb[jo][1] * ib);
            ob[1] = pack_bf16(accb[jo][2] * ib, accb[jo][3] * ib);
            *(u32x2*)(ar + jo * 16 + qd * 4) = oa;
            *(u32x2*)(br + jo * 16 + qd * 4) = ob;
        }
    }
}

// ---------------------------------------------------------------------------
extern "C" void kernel_launch(void* const* d_in, const int* in_sizes, int n_in,
                              void* d_out, int out_size, void* d_ws, size_t ws_size,
                              hipStream_t stream) {
    const float* x    = (const float*)d_in[0];   // [4,2048,1024]
    const float* Wqkv = (const float*)d_in[1];   // [1024,3072]
    const float* Wout = (const float*)d_in[2];   // [1024,1024]
    float* out = (float*)d_out;                  // [4,2048,1024] fp32

    char* ws = (char*)d_ws;
    u16* x_bf   = (u16*)(ws);                    // 16 MB
    u16* wqkv_t = (u16*)(ws + 16777216);         // 6 MB   [3072][1024]
    u16* wout_t = (u16*)(ws + 23068672);         // 2 MB   [1024][1024]
    u16* qkv_h  = (u16*)(ws + 25165824);         // 48 MB  Q,K [bh][l][64], V^T [bh][kd][2048]
    u16* att    = (u16*)(ws + 75497472);         // 16 MB  [4][2048][1024]

    prep<<<dim3(5120), dim3(256), 0, stream>>>(x, Wqkv, Wout, x_bf, wqkv_t, wout_t);
    gemm_qkv<<<dim3(1536), dim3(256), 0, stream>>>(x_bf, wqkv_t, qkv_h, 1024, 3072);
    attn_kernel<<<dim3(8, 64), dim3(256), 0, stream>>>(qkv_h, att);
    gemm_out<<<dim3(8, 128), dim3(256), 0, stream>>>(att, wout_t, out, 1024, 1024);
}

// Round 8
// 240.711 us; speedup vs baseline: 2.8504x; 1.0185x over previous
//
#include <hip/hip_runtime.h>

typedef unsigned short u16;
typedef unsigned int   u32;
typedef __bf16   bf16x8 __attribute__((ext_vector_type(8)));
typedef float    f32x4  __attribute__((ext_vector_type(4)));
typedef u16      u16x4  __attribute__((ext_vector_type(4)));
typedef u16      u16x8  __attribute__((ext_vector_type(8)));
typedef u32      u32x2  __attribute__((ext_vector_type(2)));
typedef u32      u32x4  __attribute__((ext_vector_type(4)));

#if __has_builtin(__builtin_amdgcn_exp2f)
#define EXP2(x) __builtin_amdgcn_exp2f(x)
#else
#define EXP2(x) exp2f(x)
#endif

// fp32 -> bf16 round-to-nearest-even
__device__ __forceinline__ u16 f2bf(float f) {
    unsigned u = __float_as_uint(f);
    u += 0x7FFFu + ((u >> 16) & 1u);
    return (u16)(u >> 16);
}

__device__ __forceinline__ u32 pack_bf16(float a, float b) {
#if __has_builtin(__builtin_amdgcn_cvt_pk_bf16_f32)
    typedef __bf16 bf16x2 __attribute__((ext_vector_type(2)));
    bf16x2 r = __builtin_amdgcn_cvt_pk_bf16_f32(a, b);
    return __builtin_bit_cast(u32, r);
#else
    return (u32)f2bf(a) | ((u32)f2bf(b) << 16);
#endif
}

// async global->LDS, 16 bytes/lane. LDS dest = wave-uniform base + lane*16.
__device__ __forceinline__ void async_copy16(const u16* g, u16* l) {
    __builtin_amdgcn_global_load_lds(
        (const __attribute__((address_space(1))) unsigned*)g,
        (__attribute__((address_space(3))) unsigned*)l, 16, 0, 0);
}

__device__ __forceinline__ bf16x8 lds_frag(const u16* p) {
    return *(const bf16x8*)p;
}

// gfx950 cross-lane swaps (both operands read-write).
__device__ __forceinline__ void permlane32_swap(u32& a, u32& b) {
    asm("v_permlane32_swap_b32 %0, %1" : "+v"(a), "+v"(b));
}
__device__ __forceinline__ void permlane16_swap(u32& a, u32& b) {
    asm("v_permlane16_swap_b32 %0, %1" : "+v"(a), "+v"(b));
}

// ---------------------------------------------------------------------------
// Fused prep: blocks [0,768) transpose Wqkv, [768,1024) transpose Wout,
// [1024,5120) convert x to bf16 (16 elems/thread).
__global__ __launch_bounds__(256) void prep(const float* __restrict__ x,
                                            const float* __restrict__ Wqkv,
                                            const float* __restrict__ Wout,
                                            u16* __restrict__ xb,
                                            u16* __restrict__ wqkv_t,
                                            u16* __restrict__ wout_t) {
    __shared__ u16 t[64 * 72];
    const int bid = blockIdx.x;
    const int tid = threadIdx.x;

    if (bid >= 1024) {
        // x fp32 -> bf16
        size_t i = ((size_t)(bid - 1024) * 256 + tid) * 8;
        float4 v0 = *(const float4*)(x + i);
        float4 v1 = *(const float4*)(x + i + 4);
        u16x8 o = { f2bf(v0.x), f2bf(v0.y), f2bf(v0.z), f2bf(v0.w),
                    f2bf(v1.x), f2bf(v1.y), f2bf(v1.z), f2bf(v1.w) };
        *(u16x8*)(xb + i) = o;
        return;
    }

    // W fp32 [Kd][Nd] -> Wt bf16 [Nd][Kd]
    const float* W;  u16* Wt;  int Kd, Nd, n0, k0;
    if (bid < 768) { W = Wqkv; Wt = wqkv_t; Kd = 1024; Nd = 3072;
                     n0 = (bid % 48) * 64; k0 = (bid / 48) * 64; }
    else           { W = Wout; Wt = wout_t; Kd = 1024; Nd = 1024;
                     n0 = ((bid - 768) % 16) * 64; k0 = ((bid - 768) / 16) * 64; }
#pragma unroll
    for (int i = 0; i < 4; ++i) {
        int lin = i * 256 + tid;
        int kr = lin >> 4, nc = (lin & 15) << 2;
        float4 v = *(const float4*)(W + (size_t)(k0 + kr) * Nd + n0 + nc);
        u16x4 o = { f2bf(v.x), f2bf(v.y), f2bf(v.z), f2bf(v.w) };
        *(u16x4*)&t[kr * 72 + nc] = o;
    }
    __syncthreads();
#pragma unroll
    for (int i = 0; i < 2; ++i) {
        int lin = i * 256 + tid;
        int nr = lin >> 3, kc = (lin & 7) << 3;
        u16x8 o;
#pragma unroll
        for (int jj = 0; jj < 8; ++jj) o[jj] = t[(kc + jj) * 72 + nr];
        *(u16x8*)(Wt + (size_t)(n0 + nr) * Kd + k0 + kc) = o;
    }
}

// ---------------------------------------------------------------------------
// QKV gemm: C[M,N] = A[M,K] * Bt[N,K]^T, 128x128 tile, BK=32, double-buffered
// (one barrier/iter), LDS chunk-XOR swizzle (conflict-free). Proven structure
// (74.5 us, 690 TF). XCD/L2 region mapping (R5, FETCH 71.8->41 MB verified):
// 1536 blocks, region r = flat&7 covers a 16(by) x 12(bx) rectangle.
// NOTE do-not-retry list: (a) coarse 8-phase 256^2 port (R4: -27%, occupancy
// halved, m196-coarse variant); (b) attn tile-level 2-deep S pipeline
// (R1/R6: register state > budget -> scratch spill, 2 GB traffic).
// Scatter epilogue: Q (scaled by 0.125*log2e) [bh][l][64], K [bh][l][64],
// V transposed [bh][kd][2048].
__global__ __launch_bounds__(256) void gemm_qkv(const u16* __restrict__ A,
                                                const u16* __restrict__ Bt,
                                                u16* __restrict__ outb,
                                                int K, int N) {
    __shared__ u16 As[2][128 * 32];
    __shared__ u16 Bs[2][128 * 32];
    const int tid = threadIdx.x;
    const int lane = tid & 63;
    const int wv = tid >> 6;
    const int wr = (wv >> 1) * 64;
    const int wc = (wv & 1) * 64;
    const int qd = lane >> 4;
    const int c  = lane & 15;

    // XCD/L2 region mapping (bijective over 1536 = 8 regions of 16x12 tiles)
    const int flat = blockIdx.x;
    const int r_ = flat & 7;
    const int q_ = flat >> 3;                 // 0..191
    const int m0 = ((r_ >> 1) * 16 + q_ / 12) * 128;
    const int n0 = ((r_ & 1) * 12 + q_ % 12) * 128;

    const int srow = tid >> 2;
    const int sg = ((tid & 3) ^ ((srow >> 1) & 3)) << 3;   // swizzled source chunk

    const u16* Ag0 = A  + (size_t)(m0 +      srow) * K + sg;
    const u16* Ag1 = A  + (size_t)(m0 + 64 + srow) * K + sg;
    const u16* Bg0 = Bt + (size_t)(n0 +      srow) * K + sg;
    const u16* Bg1 = Bt + (size_t)(n0 + 64 + srow) * K + sg;

    const u32 fsw = (qd ^ ((c >> 1) & 3)) << 3;            // swizzled frag chunk
    const u32 a_off = (wr + c) * 32 + fsw;                 // + i*512
    const u32 b_off = (wc + c) * 32 + fsw;                 // + j*512

    f32x4 acc[4][4] = {};

    async_copy16(Ag0, &As[0][tid * 8]);
    async_copy16(Ag1, &As[0][2048 + tid * 8]);
    async_copy16(Bg0, &Bs[0][tid * 8]);
    async_copy16(Bg1, &Bs[0][2048 + tid * 8]);

    int p = 0;
    for (int k0 = 0; k0 < K; k0 += 32) {
        __syncthreads();
        if (k0 + 32 < K) {
            const int np = p ^ 1;
            async_copy16(Ag0 + k0 + 32, &As[np][tid * 8]);
            async_copy16(Ag1 + k0 + 32, &As[np][2048 + tid * 8]);
            async_copy16(Bg0 + k0 + 32, &Bs[np][tid * 8]);
            async_copy16(Bg1 + k0 + 32, &Bs[np][2048 + tid * 8]);
        }
        bf16x8 af[4], bfr[4];
#pragma unroll
        for (int i = 0; i < 4; ++i) af[i]  = lds_frag(&As[p][a_off + i * 512]);
#pragma unroll
        for (int j = 0; j < 4; ++j) bfr[j] = lds_frag(&Bs[p][b_off + j * 512]);
#pragma unroll
        for (int i = 0; i < 4; ++i)
#pragma unroll
            for (int j = 0; j < 4; ++j)
                acc[i][j] = __builtin_amdgcn_mfma_f32_16x16x32_bf16(af[i], bfr[j], acc[i][j], 0, 0, 0);
        p ^= 1;
    }

    // C/D layout: col = lane&15, row = (lane>>4)*4 + reg
#pragma unroll
    for (int i = 0; i < 4; ++i)
#pragma unroll
        for (int j = 0; j < 4; ++j) {
            int n = n0 + wc + j * 16 + c;
            int which = n >> 10, h = (n >> 6) & 15, kd = n & 63;
            int m_base = m0 + wr + i * 16 + qd * 4;
            int b = m_base >> 11, l0 = m_base & 2047;
            int bh = b * 16 + h;
            if (which == 2) {
                u32x2 o2;
                o2[0] = pack_bf16(acc[i][j][0], acc[i][j][1]);
                o2[1] = pack_bf16(acc[i][j][2], acc[i][j][3]);
                *(u32x2*)(outb + (size_t)(128 + bh) * 131072 + (size_t)kd * 2048 + l0) = o2;
            } else if (which == 0) {
#pragma unroll
                for (int r = 0; r < 4; ++r)
                    outb[(size_t)bh * 131072 + (size_t)(l0 + r) * 64 + kd] =
                        f2bf(acc[i][j][r] * 0.1803368801f);   // 0.125*log2(e)
            } else {
#pragma unroll
                for (int r = 0; r < 4; ++r)
                    outb[(size_t)(64 + bh) * 131072 + (size_t)(l0 + r) * 64 + kd] =
                        f2bf(acc[i][j][r]);
            }
        }
}

// ---------------------------------------------------------------------------
// Output gemm, round-8: exact clone of the proven gemm_qkv main loop
// (128x128 tile, BK=32, double-buffered, one barrier/iter, XOR swizzle)
// with a plain fp32 epilogue. Old 64x128 structure had half the MFMA
// density per staging/barrier (8 MFMA vs 16 per wave-iter) -> est ~40 us;
// this template measures ~690 TF at K=1024 -> 17.2 GF in ~25 us.
// Grid 512 = 64 M-tiles x 8 N-tiles; XCD regioning: region r = flat&7
// covers 8 M-tiles x all 8 N-tiles (A 2MB + B 2MB = one XCD L2).
__global__ __launch_bounds__(256) void gemm_out(const u16* __restrict__ A,
                                                const u16* __restrict__ Bt,
                                                float* __restrict__ outf,
                                                int K, int N) {
    __shared__ u16 As[2][128 * 32];
    __shared__ u16 Bs[2][128 * 32];
    const int tid = threadIdx.x;
    const int lane = tid & 63;
    const int wv = tid >> 6;
    const int wr = (wv >> 1) * 64;
    const int wc = (wv & 1) * 64;
    const int qd = lane >> 4;
    const int c  = lane & 15;

    // bijective over 512 = 8 regions x (8 mtiles x 8 ntiles)
    const int flat = blockIdx.x;
    const int r_ = flat & 7;
    const int q_ = flat >> 3;                 // 0..63
    const int m0 = (r_ * 8 + (q_ >> 3)) * 128;
    const int n0 = (q_ & 7) * 128;

    const int srow = tid >> 2;
    const int sg = ((tid & 3) ^ ((srow >> 1) & 3)) << 3;

    const u16* Ag0 = A  + (size_t)(m0 +      srow) * K + sg;
    const u16* Ag1 = A  + (size_t)(m0 + 64 + srow) * K + sg;
    const u16* Bg0 = Bt + (size_t)(n0 +      srow) * K + sg;
    const u16* Bg1 = Bt + (size_t)(n0 + 64 + srow) * K + sg;

    const u32 fsw = (qd ^ ((c >> 1) & 3)) << 3;
    const u32 a_off = (wr + c) * 32 + fsw;                 // + i*512
    const u32 b_off = (wc + c) * 32 + fsw;                 // + j*512

    f32x4 acc[4][4] = {};

    async_copy16(Ag0, &As[0][tid * 8]);
    async_copy16(Ag1, &As[0][2048 + tid * 8]);
    async_copy16(Bg0, &Bs[0][tid * 8]);
    async_copy16(Bg1, &Bs[0][2048 + tid * 8]);

    int p = 0;
    for (int k0 = 0; k0 < K; k0 += 32) {
        __syncthreads();
        if (k0 + 32 < K) {
            const int np = p ^ 1;
            async_copy16(Ag0 + k0 + 32, &As[np][tid * 8]);
            async_copy16(Ag1 + k0 + 32, &As[np][2048 + tid * 8]);
            async_copy16(Bg0 + k0 + 32, &Bs[np][tid * 8]);
            async_copy16(Bg1 + k0 + 32, &Bs[np][2048 + tid * 8]);
        }
        bf16x8 af[4], bfr[4];
#pragma unroll
        for (int i = 0; i < 4; ++i) af[i]  = lds_frag(&As[p][a_off + i * 512]);
#pragma unroll
        for (int j = 0; j < 4; ++j) bfr[j] = lds_frag(&Bs[p][b_off + j * 512]);
#pragma unroll
        for (int i = 0; i < 4; ++i)
#pragma unroll
            for (int j = 0; j < 4; ++j)
                acc[i][j] = __builtin_amdgcn_mfma_f32_16x16x32_bf16(af[i], bfr[j], acc[i][j], 0, 0, 0);
        p ^= 1;
    }

    // C/D layout: col = lane&15, row = (lane>>4)*4 + reg
#pragma unroll
    for (int i = 0; i < 4; ++i)
#pragma unroll
        for (int j = 0; j < 4; ++j) {
            int n = n0 + wc + j * 16 + c;
            int m_base = m0 + wr + i * 16 + qd * 4;
#pragma unroll
            for (int r = 0; r < 4; ++r)
                outf[(size_t)(m_base + r) * N + n] = acc[i][j][r];
        }
}

// ---------------------------------------------------------------------------
// Flash attention, causal, S^T form (round-3 fused-stream version, verified:
// ~73 us, WRITE ~20.5 MB, no scratch). Fused a/b streams: each K fragment
// read feeds BOTH sa and sb MFMAs; each V fragment read feeds acca and accb
// (32 ds_read/tile). In-register P^T via v_permlane{32,16}_swap, exp2 bias
// -8 folded into MFMA C-init, packed f32x4 row-sums, setprio on MFMA
// clusters, K/V double-buffered (64 KB -> 2 blocks/CU), one barrier/tile.
#define ATTN_S_AB(KSB)                                                        \
    do {                                                                      \
        _Pragma("unroll") for (int f = 0; f < 8; ++f) {                       \
            sa[f] = f32x4{-8.f, -8.f, -8.f, -8.f};                            \
            sb[f] = f32x4{-8.f, -8.f, -8.f, -8.f};                            \
        }                                                                     \
        __builtin_amdgcn_s_setprio(1);                                        \
        _Pragma("unroll") for (int ks = 0; ks < 2; ++ks) {                    \
            const u16* kp = (KSB) + kf_off[ks];                               \
            _Pragma("unroll") for (int f = 0; f < 8; ++f) {                   \
                bf16x8 kf = lds_frag(kp + f * 1024);                          \
                sa[f] = __builtin_amdgcn_mfma_f32_16x16x32_bf16(              \
                    kf, qa[ks], sa[f], 0, 0, 0);                              \
                sb[f] = __builtin_amdgcn_mfma_f32_16x16x32_bf16(              \
                    kf, qb[ks], sb[f], 0, 0, 0);                              \
            }                                                                 \
        }                                                                     \
        __builtin_amdgcn_s_setprio(0);                                        \
    } while (0)

#define ATTN_FINISH_AB(VTB, KT)                                               \
    do {                                                                      \
        if ((KT) == qt) {                                                     \
            _Pragma("unroll") for (int f = 0; f < 8; ++f)                     \
                _Pragma("unroll") for (int r = 0; r < 4; ++r) {               \
                    int key = (KT) * 128 + f * 16 + qd * 4 + r;               \
                    if (key > qa_row) sa[f][r] = -3e38f;                      \
                    if (key > qb_row) sb[f][r] = -3e38f;                      \
                }                                                             \
        }                                                                     \
        _Pragma("unroll") for (int f = 0; f < 8; ++f) {                       \
            _Pragma("unroll") for (int r = 0; r < 4; ++r) {                   \
                sa[f][r] = EXP2(sa[f][r]);                                    \
                sb[f][r] = EXP2(sb[f][r]);                                    \
            }                                                                 \
            rva += sa[f];                                                     \
            rvb += sb[f];                                                     \
        }                                                                     \
        _Pragma("unroll") for (int kc = 0; kc < 4; ++kc) {                    \
            u32 a0 = pack_bf16(sa[2 * kc][0], sa[2 * kc][1]);                 \
            u32 a1 = pack_bf16(sa[2 * kc + 1][0], sa[2 * kc + 1][1]);         \
            u32 b0 = pack_bf16(sa[2 * kc][2], sa[2 * kc][3]);                 \
            u32 b1 = pack_bf16(sa[2 * kc + 1][2], sa[2 * kc + 1][3]);         \
            permlane32_swap(a0, a1); permlane16_swap(a0, a1);                 \
            permlane32_swap(b0, b1); permlane16_swap(b0, b1);                 \
            u32x4 wpa = {a0, b0, a1, b1};                                     \
            bf16x8 pa = __builtin_bit_cast(bf16x8, wpa);                      \
            u32 c0 = pack_bf16(sb[2 * kc][0], sb[2 * kc][1]);                 \
            u32 c1 = pack_bf16(sb[2 * kc + 1][0], sb[2 * kc + 1][1]);         \
            u32 d0 = pack_bf16(sb[2 * kc][2], sb[2 * kc][3]);                 \
            u32 d1 = pack_bf16(sb[2 * kc + 1][2], sb[2 * kc + 1][3]);         \
            permlane32_swap(c0, c1); permlane16_swap(c0, c1);                 \
            permlane32_swap(d0, d1); permlane16_swap(d0, d1);                 \
            u32x4 wpb = {c0, d0, c1, d1};                                     \
            bf16x8 pb = __builtin_bit_cast(bf16x8, wpb);                      \
            const u16* vp = (VTB) + vf_off[kc];                               \
            __builtin_amdgcn_s_setprio(1);                                    \
            _Pragma("unroll") for (int jo = 0; jo < 4; ++jo) {                \
                bf16x8 vf = lds_frag(vp + jo * 2048);                         \
                acca[jo] = __builtin_amdgcn_mfma_f32_16x16x32_bf16(           \
                    vf, pa, acca[jo], 0, 0, 0);                               \
                accb[jo] = __builtin_amdgcn_mfma_f32_16x16x32_bf16(           \
                    vf, pb, accb[jo], 0, 0, 0);                               \
            }                                                                 \
            __builtin_amdgcn_s_setprio(0);                                    \
        }                                                                     \
    } while (0)

__global__ __launch_bounds__(256, 2) void attn_kernel(const u16* __restrict__ qkv,
                                                      u16* __restrict__ att) {
    __shared__ u16 Ks[2][128 * 64];   // [key][kd], 16B-chunk XOR swizzled
    __shared__ u16 Vt[2][64 * 128];   // [kd][key], 16B-chunk XOR swizzled

    const int tid = threadIdx.x;
    const int lane = tid & 63;
    const int w = tid >> 6;
    const int qd = lane >> 4;
    const int c = lane & 15;

    // XCD swizzle: flat%8 == bh%8 -> one bh's K/V stays in one XCD L2
    const int flat = blockIdx.x + 8 * blockIdx.y;
    const int bh = (flat & 7) + 8 * ((flat >> 3) & 7);
    const int bx = flat >> 6;
    const int b = bh >> 4, h = bh & 15;

    const u16* Qg = qkv + (size_t)bh * 131072;
    const u16* Kg = qkv + (size_t)(64 + bh) * 131072;
    const u16* Vg = qkv + (size_t)(128 + bh) * 131072;   // [kd][2048]

    u32 kf_off[2];
#pragma unroll
    for (int ks = 0; ks < 2; ++ks)
        kf_off[ks] = c * 64 + (((ks * 4 + qd) ^ (c & 7)) << 3);
    u32 vf_off[4];
#pragma unroll
    for (int kc = 0; kc < 4; ++kc)
        vf_off[kc] = c * 128 + (((kc * 4 + qd) ^ c) << 3);

    // 8 x 16B async copies per tile (K and V), pre-swizzled global source,
    // linear LDS dest (global_load_lds requirement). Writes LDS only.
    auto issue_copy = [&](int t, u16* kd, u16* vd) {
#pragma unroll
        for (int it = 0; it < 4; ++it) {
            int lin = it * 256 + tid;
            int krw = lin >> 3, kch = lin & 7;
            int vrw = lin >> 4, vch = lin & 15;
            async_copy16(Kg + (size_t)t * 8192 + krw * 64 + ((kch ^ (krw & 7)) << 3),
                         kd + lin * 8);
            async_copy16(Vg + (size_t)t * 128 + (size_t)vrw * 2048 + ((vch ^ (vrw & 15)) << 3),
                         vd + lin * 8);
        }
    };

#pragma unroll 1
    for (int seg = 0; seg < 2; ++seg) {
        const int qt = seg ? (15 - bx) : bx;            // balanced causal pairing
        const int qa_row = qt * 128 + w * 32 + c;       // frag a
        const int qb_row = qa_row + 16;                 // frag b

        bf16x8 qa[2], qb[2];
#pragma unroll
        for (int ks = 0; ks < 2; ++ks) {
            qa[ks] = *(const bf16x8*)(Qg + (size_t)qa_row * 64 + ks * 32 + qd * 8);
            qb[ks] = *(const bf16x8*)(Qg + (size_t)qb_row * 64 + ks * 32 + qd * 8);
        }

        f32x4 acca[4] = {}, accb[4] = {};
        f32x4 rva = {}, rvb = {};                        // packed row-sum accum
        f32x4 sa[8], sb[8];

        const int nkt = qt + 1;

        // ---- prologue: tile 0 staged; tile 1 issued ----
        __syncthreads();                     // prev-seg readers done with bufs
        issue_copy(0, Ks[0], Vt[0]);
        __syncthreads();                     // tile 0 landed (all waves)
        if (nkt > 1) issue_copy(1, Ks[1], Vt[1]);

#pragma unroll 1
        for (int kt = 0; kt < nkt; ++kt) {
            const int p = kt & 1;
            ATTN_S_AB(Ks[p]);                // 32 MFMA, 16 shared kf reads
            ATTN_FINISH_AB(Vt[p], kt);       // exp2/permlane + 32 MFMA, 16 vf reads
            if (kt + 1 < nkt) {
                __syncthreads();             // tile kt+1 landed; buf p free
                if (kt + 2 < nkt) issue_copy(kt + 2, Ks[p], Vt[p]);
            }
        }

        // epilogue: reduce row-sums across the 4 quad-groups, then scale
        float ra = rva[0] + rva[1] + rva[2] + rva[3];
        float rb = rvb[0] + rvb[1] + rvb[2] + rvb[3];
        ra += __shfl_xor(ra, 16, 64);
        ra += __shfl_xor(ra, 32, 64);
        rb += __shfl_xor(rb, 16, 64);
        rb += __shfl_xor(rb, 32, 64);
        float ia = __builtin_amdgcn_rcpf(ra), ib = __builtin_amdgcn_rcpf(rb);
        u16* ar = att + ((size_t)b * 2048 + qa_row) * 1024 + h * 64;
        u16* br = att + ((size_t)b * 2048 + qb_row) * 1024 + h * 64;
#pragma unroll
        for (int jo = 0; jo < 4; ++jo) {
            u32x2 oa, ob;
            oa[0] = pack_bf16(acca[jo][0] * ia, acca[jo][1] * ia);
            oa[1] = pack_bf16(acca[jo][2] * ia, acca[jo][3] * ia);
            ob[0] = pack_bf16(accb[jo][0] * ib, accb[jo][1] * ib);
            ob[1] = pack_bf16(accb[jo][2] * ib, accb[jo][3] * ib);
            *(u32x2*)(ar + jo * 16 + qd * 4) = oa;
            *(u32x2*)(br + jo * 16 + qd * 4) = ob;
        }
    }
}

// ---------------------------------------------------------------------------
extern "C" void kernel_launch(void* const* d_in, const int* in_sizes, int n_in,
                              void* d_out, int out_size, void* d_ws, size_t ws_size,
                              hipStream_t stream) {
    const float* x    = (const float*)d_in[0];   // [4,2048,1024]
    const float* Wqkv = (const float*)d_in[1];   // [1024,3072]
    const float* Wout = (const float*)d_in[2];   // [1024,1024]
    float* out = (float*)d_out;                  // [4,2048,1024] fp32

    char* ws = (char*)d_ws;
    u16* x_bf   = (u16*)(ws);                    // 16 MB
    u16* wqkv_t = (u16*)(ws + 16777216);         // 6 MB   [3072][1024]
    u16* wout_t = (u16*)(ws + 23068672);         // 2 MB   [1024][1024]
    u16* qkv_h  = (u16*)(ws + 25165824);         // 48 MB  Q,K [bh][l][64], V^T [bh][kd][2048]
    u16* att    = (u16*)(ws + 75497472);         // 16 MB  [4][2048][1024]

    prep<<<dim3(5120), dim3(256), 0, stream>>>(x, Wqkv, Wout, x_bf, wqkv_t, wout_t);
    gemm_qkv<<<dim3(1536), dim3(256), 0, stream>>>(x_bf, wqkv_t, qkv_h, 1024, 3072);
    attn_kernel<<<dim3(8, 64), dim3(256), 0, stream>>>(qkv_h, att);
    gemm_out<<<dim3(512), dim3(256), 0, stream>>>(att, wout_t, out, 1024, 1024);
}

// Round 9
// 239.067 us; speedup vs baseline: 2.8700x; 1.0069x over previous
//
#include <hip/hip_runtime.h>

typedef unsigned short u16;
typedef unsigned int   u32;
typedef __bf16   bf16x8 __attribute__((ext_vector_type(8)));
typedef float    f32x4  __attribute__((ext_vector_type(4)));
typedef u16      u16x4  __attribute__((ext_vector_type(4)));
typedef u16      u16x8  __attribute__((ext_vector_type(8)));
typedef u32      u32x2  __attribute__((ext_vector_type(2)));
typedef u32      u32x4  __attribute__((ext_vector_type(4)));

#if __has_builtin(__builtin_amdgcn_exp2f)
#define EXP2(x) __builtin_amdgcn_exp2f(x)
#else
#define EXP2(x) exp2f(x)
#endif

// fp32 -> bf16 round-to-nearest-even
__device__ __forceinline__ u16 f2bf(float f) {
    unsigned u = __float_as_uint(f);
    u += 0x7FFFu + ((u >> 16) & 1u);
    return (u16)(u >> 16);
}

__device__ __forceinline__ u32 pack_bf16(float a, float b) {
#if __has_builtin(__builtin_amdgcn_cvt_pk_bf16_f32)
    typedef __bf16 bf16x2 __attribute__((ext_vector_type(2)));
    bf16x2 r = __builtin_amdgcn_cvt_pk_bf16_f32(a, b);
    return __builtin_bit_cast(u32, r);
#else
    return (u32)f2bf(a) | ((u32)f2bf(b) << 16);
#endif
}

// async global->LDS, 16 bytes/lane. LDS dest = wave-uniform base + lane*16.
__device__ __forceinline__ void async_copy16(const u16* g, u16* l) {
    __builtin_amdgcn_global_load_lds(
        (const __attribute__((address_space(1))) unsigned*)g,
        (__attribute__((address_space(3))) unsigned*)l, 16, 0, 0);
}

__device__ __forceinline__ bf16x8 lds_frag(const u16* p) {
    return *(const bf16x8*)p;
}

// gfx950 cross-lane swaps (both operands read-write).
__device__ __forceinline__ void permlane32_swap(u32& a, u32& b) {
    asm("v_permlane32_swap_b32 %0, %1" : "+v"(a), "+v"(b));
}
__device__ __forceinline__ void permlane16_swap(u32& a, u32& b) {
    asm("v_permlane16_swap_b32 %0, %1" : "+v"(a), "+v"(b));
}

// ---------------------------------------------------------------------------
// Fused prep: blocks [0,768) transpose Wqkv, [768,1024) transpose Wout,
// [1024,5120) convert x to bf16 (16 elems/thread).
__global__ __launch_bounds__(256) void prep(const float* __restrict__ x,
                                            const float* __restrict__ Wqkv,
                                            const float* __restrict__ Wout,
                                            u16* __restrict__ xb,
                                            u16* __restrict__ wqkv_t,
                                            u16* __restrict__ wout_t) {
    __shared__ u16 t[64 * 72];
    const int bid = blockIdx.x;
    const int tid = threadIdx.x;

    if (bid >= 1024) {
        // x fp32 -> bf16
        size_t i = ((size_t)(bid - 1024) * 256 + tid) * 8;
        float4 v0 = *(const float4*)(x + i);
        float4 v1 = *(const float4*)(x + i + 4);
        u16x8 o = { f2bf(v0.x), f2bf(v0.y), f2bf(v0.z), f2bf(v0.w),
                    f2bf(v1.x), f2bf(v1.y), f2bf(v1.z), f2bf(v1.w) };
        *(u16x8*)(xb + i) = o;
        return;
    }

    // W fp32 [Kd][Nd] -> Wt bf16 [Nd][Kd]
    const float* W;  u16* Wt;  int Kd, Nd, n0, k0;
    if (bid < 768) { W = Wqkv; Wt = wqkv_t; Kd = 1024; Nd = 3072;
                     n0 = (bid % 48) * 64; k0 = (bid / 48) * 64; }
    else           { W = Wout; Wt = wout_t; Kd = 1024; Nd = 1024;
                     n0 = ((bid - 768) % 16) * 64; k0 = ((bid - 768) / 16) * 64; }
#pragma unroll
    for (int i = 0; i < 4; ++i) {
        int lin = i * 256 + tid;
        int kr = lin >> 4, nc = (lin & 15) << 2;
        float4 v = *(const float4*)(W + (size_t)(k0 + kr) * Nd + n0 + nc);
        u16x4 o = { f2bf(v.x), f2bf(v.y), f2bf(v.z), f2bf(v.w) };
        *(u16x4*)&t[kr * 72 + nc] = o;
    }
    __syncthreads();
#pragma unroll
    for (int i = 0; i < 2; ++i) {
        int lin = i * 256 + tid;
        int nr = lin >> 3, kc = (lin & 7) << 3;
        u16x8 o;
#pragma unroll
        for (int jj = 0; jj < 8; ++jj) o[jj] = t[(kc + jj) * 72 + nr];
        *(u16x8*)(Wt + (size_t)(n0 + nr) * Kd + k0 + kc) = o;
    }
}

// ---------------------------------------------------------------------------
// QKV gemm: C[M,N] = A[M,K] * Bt[N,K]^T, 128x128 tile, BK=32, double-buffered
// (one barrier/iter), LDS chunk-XOR swizzle (conflict-free). Proven structure
// (74 us, 690 TF). XCD/L2 region mapping (FETCH 71.8->41 MB verified).
// Do-not-retry list: (a) coarse 8-phase 256^2 port (R4: -27%); (b) attn
// tile-level 2-deep S pipeline (R1/R6: scratch spill).
__global__ __launch_bounds__(256) void gemm_qkv(const u16* __restrict__ A,
                                                const u16* __restrict__ Bt,
                                                u16* __restrict__ outb,
                                                int K, int N) {
    __shared__ u16 As[2][128 * 32];
    __shared__ u16 Bs[2][128 * 32];
    const int tid = threadIdx.x;
    const int lane = tid & 63;
    const int wv = tid >> 6;
    const int wr = (wv >> 1) * 64;
    const int wc = (wv & 1) * 64;
    const int qd = lane >> 4;
    const int c  = lane & 15;

    // XCD/L2 region mapping (bijective over 1536 = 8 regions of 16x12 tiles)
    const int flat = blockIdx.x;
    const int r_ = flat & 7;
    const int q_ = flat >> 3;                 // 0..191
    const int m0 = ((r_ >> 1) * 16 + q_ / 12) * 128;
    const int n0 = ((r_ & 1) * 12 + q_ % 12) * 128;

    const int srow = tid >> 2;
    const int sg = ((tid & 3) ^ ((srow >> 1) & 3)) << 3;   // swizzled source chunk

    const u16* Ag0 = A  + (size_t)(m0 +      srow) * K + sg;
    const u16* Ag1 = A  + (size_t)(m0 + 64 + srow) * K + sg;
    const u16* Bg0 = Bt + (size_t)(n0 +      srow) * K + sg;
    const u16* Bg1 = Bt + (size_t)(n0 + 64 + srow) * K + sg;

    const u32 fsw = (qd ^ ((c >> 1) & 3)) << 3;            // swizzled frag chunk
    const u32 a_off = (wr + c) * 32 + fsw;                 // + i*512
    const u32 b_off = (wc + c) * 32 + fsw;                 // + j*512

    f32x4 acc[4][4] = {};

    async_copy16(Ag0, &As[0][tid * 8]);
    async_copy16(Ag1, &As[0][2048 + tid * 8]);
    async_copy16(Bg0, &Bs[0][tid * 8]);
    async_copy16(Bg1, &Bs[0][2048 + tid * 8]);

    int p = 0;
    for (int k0 = 0; k0 < K; k0 += 32) {
        __syncthreads();
        if (k0 + 32 < K) {
            const int np = p ^ 1;
            async_copy16(Ag0 + k0 + 32, &As[np][tid * 8]);
            async_copy16(Ag1 + k0 + 32, &As[np][2048 + tid * 8]);
            async_copy16(Bg0 + k0 + 32, &Bs[np][tid * 8]);
            async_copy16(Bg1 + k0 + 32, &Bs[np][2048 + tid * 8]);
        }
        bf16x8 af[4], bfr[4];
#pragma unroll
        for (int i = 0; i < 4; ++i) af[i]  = lds_frag(&As[p][a_off + i * 512]);
#pragma unroll
        for (int j = 0; j < 4; ++j) bfr[j] = lds_frag(&Bs[p][b_off + j * 512]);
#pragma unroll
        for (int i = 0; i < 4; ++i)
#pragma unroll
            for (int j = 0; j < 4; ++j)
                acc[i][j] = __builtin_amdgcn_mfma_f32_16x16x32_bf16(af[i], bfr[j], acc[i][j], 0, 0, 0);
        p ^= 1;
    }

    // C/D layout: col = lane&15, row = (lane>>4)*4 + reg
#pragma unroll
    for (int i = 0; i < 4; ++i)
#pragma unroll
        for (int j = 0; j < 4; ++j) {
            int n = n0 + wc + j * 16 + c;
            int which = n >> 10, h = (n >> 6) & 15, kd = n & 63;
            int m_base = m0 + wr + i * 16 + qd * 4;
            int b = m_base >> 11, l0 = m_base & 2047;
            int bh = b * 16 + h;
            if (which == 2) {
                u32x2 o2;
                o2[0] = pack_bf16(acc[i][j][0], acc[i][j][1]);
                o2[1] = pack_bf16(acc[i][j][2], acc[i][j][3]);
                *(u32x2*)(outb + (size_t)(128 + bh) * 131072 + (size_t)kd * 2048 + l0) = o2;
            } else if (which == 0) {
#pragma unroll
                for (int r = 0; r < 4; ++r)
                    outb[(size_t)bh * 131072 + (size_t)(l0 + r) * 64 + kd] =
                        f2bf(acc[i][j][r] * 0.1803368801f);   // 0.125*log2(e)
            } else {
#pragma unroll
                for (int r = 0; r < 4; ++r)
                    outb[(size_t)(64 + bh) * 131072 + (size_t)(l0 + r) * 64 + kd] =
                        f2bf(acc[i][j][r]);
            }
        }
}

// ---------------------------------------------------------------------------
// Output gemm (R8 clone of gemm_qkv main loop, verified): 128x128, BK=32,
// double-buffered, XOR swizzle, fp32 epilogue. 512 blocks, XCD regioning.
__global__ __launch_bounds__(256) void gemm_out(const u16* __restrict__ A,
                                                const u16* __restrict__ Bt,
                                                float* __restrict__ outf,
                                                int K, int N) {
    __shared__ u16 As[2][128 * 32];
    __shared__ u16 Bs[2][128 * 32];
    const int tid = threadIdx.x;
    const int lane = tid & 63;
    const int wv = tid >> 6;
    const int wr = (wv >> 1) * 64;
    const int wc = (wv & 1) * 64;
    const int qd = lane >> 4;
    const int c  = lane & 15;

    // bijective over 512 = 8 regions x (8 mtiles x 8 ntiles)
    const int flat = blockIdx.x;
    const int r_ = flat & 7;
    const int q_ = flat >> 3;                 // 0..63
    const int m0 = (r_ * 8 + (q_ >> 3)) * 128;
    const int n0 = (q_ & 7) * 128;

    const int srow = tid >> 2;
    const int sg = ((tid & 3) ^ ((srow >> 1) & 3)) << 3;

    const u16* Ag0 = A  + (size_t)(m0 +      srow) * K + sg;
    const u16* Ag1 = A  + (size_t)(m0 + 64 + srow) * K + sg;
    const u16* Bg0 = Bt + (size_t)(n0 +      srow) * K + sg;
    const u16* Bg1 = Bt + (size_t)(n0 + 64 + srow) * K + sg;

    const u32 fsw = (qd ^ ((c >> 1) & 3)) << 3;
    const u32 a_off = (wr + c) * 32 + fsw;                 // + i*512
    const u32 b_off = (wc + c) * 32 + fsw;                 // + j*512

    f32x4 acc[4][4] = {};

    async_copy16(Ag0, &As[0][tid * 8]);
    async_copy16(Ag1, &As[0][2048 + tid * 8]);
    async_copy16(Bg0, &Bs[0][tid * 8]);
    async_copy16(Bg1, &Bs[0][2048 + tid * 8]);

    int p = 0;
    for (int k0 = 0; k0 < K; k0 += 32) {
        __syncthreads();
        if (k0 + 32 < K) {
            const int np = p ^ 1;
            async_copy16(Ag0 + k0 + 32, &As[np][tid * 8]);
            async_copy16(Ag1 + k0 + 32, &As[np][2048 + tid * 8]);
            async_copy16(Bg0 + k0 + 32, &Bs[np][tid * 8]);
            async_copy16(Bg1 + k0 + 32, &Bs[np][2048 + tid * 8]);
        }
        bf16x8 af[4], bfr[4];
#pragma unroll
        for (int i = 0; i < 4; ++i) af[i]  = lds_frag(&As[p][a_off + i * 512]);
#pragma unroll
        for (int j = 0; j < 4; ++j) bfr[j] = lds_frag(&Bs[p][b_off + j * 512]);
#pragma unroll
        for (int i = 0; i < 4; ++i)
#pragma unroll
            for (int j = 0; j < 4; ++j)
                acc[i][j] = __builtin_amdgcn_mfma_f32_16x16x32_bf16(af[i], bfr[j], acc[i][j], 0, 0, 0);
        p ^= 1;
    }

    // C/D layout: col = lane&15, row = (lane>>4)*4 + reg
#pragma unroll
    for (int i = 0; i < 4; ++i)
#pragma unroll
        for (int j = 0; j < 4; ++j) {
            int n = n0 + wc + j * 16 + c;
            int m_base = m0 + wr + i * 16 + qd * 4;
#pragma unroll
            for (int r = 0; r < 4; ++r)
                outf[(size_t)(m_base + r) * N + n] = acc[i][j][r];
        }
}

// ---------------------------------------------------------------------------
// Flash attention, causal, S^T form. Round-9: MERGED causal segments.
// Each block owns Q-tiles qt0=bx and qt1=15-bx. Instead of two sequential
// passes each staging K/V tiles 0..qt, ONE loop over kt=0..qt1 stages each
// tile once; both segments consume it (seg0 only while kt<=qt0). Staging
// tiles/block: 17 -> 16-bx (avg 12.5, -26%); barriers likewise. Compute
// work unchanged. Segments processed SEQUENTIALLY within a tile so only one
// sa/sb set is live (peak ~200 VGPR < 256 cap at 2 waves/SIMD -- R6 lesson).
// All other techniques unchanged from the verified R3 kernel.
#define ATTN_S(KSB, QA, QB)                                                   \
    do {                                                                      \
        _Pragma("unroll") for (int f = 0; f < 8; ++f) {                       \
            sa[f] = f32x4{-8.f, -8.f, -8.f, -8.f};                            \
            sb[f] = f32x4{-8.f, -8.f, -8.f, -8.f};                            \
        }                                                                     \
        __builtin_amdgcn_s_setprio(1);                                        \
        _Pragma("unroll") for (int ks = 0; ks < 2; ++ks) {                    \
            const u16* kp = (KSB) + kf_off[ks];                               \
            _Pragma("unroll") for (int f = 0; f < 8; ++f) {                   \
                bf16x8 kf = lds_frag(kp + f * 1024);                          \
                sa[f] = __builtin_amdgcn_mfma_f32_16x16x32_bf16(              \
                    kf, QA[ks], sa[f], 0, 0, 0);                              \
                sb[f] = __builtin_amdgcn_mfma_f32_16x16x32_bf16(              \
                    kf, QB[ks], sb[f], 0, 0, 0);                              \
            }                                                                 \
        }                                                                     \
        __builtin_amdgcn_s_setprio(0);                                        \
    } while (0)

#define ATTN_FIN(VTB, KT, QT, QAROW, QBROW, RVA, RVB, ACCA, ACCB)             \
    do {                                                                      \
        if ((KT) == (QT)) {                                                   \
            _Pragma("unroll") for (int f = 0; f < 8; ++f)                     \
                _Pragma("unroll") for (int r = 0; r < 4; ++r) {               \
                    int key = (KT) * 128 + f * 16 + qd * 4 + r;               \
                    if (key > (QAROW)) sa[f][r] = -3e38f;                     \
                    if (key > (QBROW)) sb[f][r] = -3e38f;                     \
                }                                                             \
        }                                                                     \
        _Pragma("unroll") for (int f = 0; f < 8; ++f) {                       \
            _Pragma("unroll") for (int r = 0; r < 4; ++r) {                   \
                sa[f][r] = EXP2(sa[f][r]);                                    \
                sb[f][r] = EXP2(sb[f][r]);                                    \
            }                                                                 \
            RVA += sa[f];                                                     \
            RVB += sb[f];                                                     \
        }                                                                     \
        _Pragma("unroll") for (int kc = 0; kc < 4; ++kc) {                    \
            u32 a0 = pack_bf16(sa[2 * kc][0], sa[2 * kc][1]);                 \
            u32 a1 = pack_bf16(sa[2 * kc + 1][0], sa[2 * kc + 1][1]);         \
            u32 b0 = pack_bf16(sa[2 * kc][2], sa[2 * kc][3]);                 \
            u32 b1 = pack_bf16(sa[2 * kc + 1][2], sa[2 * kc + 1][3]);         \
            permlane32_swap(a0, a1); permlane16_swap(a0, a1);                 \
            permlane32_swap(b0, b1); permlane16_swap(b0, b1);                 \
            u32x4 wpa = {a0, b0, a1, b1};                                     \
            bf16x8 pa = __builtin_bit_cast(bf16x8, wpa);                      \
            u32 c0 = pack_bf16(sb[2 * kc][0], sb[2 * kc][1]);                 \
            u32 c1 = pack_bf16(sb[2 * kc + 1][0], sb[2 * kc + 1][1]);         \
            u32 d0 = pack_bf16(sb[2 * kc][2], sb[2 * kc][3]);                 \
            u32 d1 = pack_bf16(sb[2 * kc + 1][2], sb[2 * kc + 1][3]);         \
            permlane32_swap(c0, c1); permlane16_swap(c0, c1);                 \
            permlane32_swap(d0, d1); permlane16_swap(d0, d1);                 \
            u32x4 wpb = {c0, d0, c1, d1};                                     \
            bf16x8 pb = __builtin_bit_cast(bf16x8, wpb);                      \
            const u16* vp = (VTB) + vf_off[kc];                               \
            __builtin_amdgcn_s_setprio(1);                                    \
            _Pragma("unroll") for (int jo = 0; jo < 4; ++jo) {                \
                bf16x8 vf = lds_frag(vp + jo * 2048);                         \
                ACCA[jo] = __builtin_amdgcn_mfma_f32_16x16x32_bf16(           \
                    vf, pa, ACCA[jo], 0, 0, 0);                               \
                ACCB[jo] = __builtin_amdgcn_mfma_f32_16x16x32_bf16(           \
                    vf, pb, ACCB[jo], 0, 0, 0);                               \
            }                                                                 \
            __builtin_amdgcn_s_setprio(0);                                    \
        }                                                                     \
    } while (0)

__global__ __launch_bounds__(256, 2) void attn_kernel(const u16* __restrict__ qkv,
                                                      u16* __restrict__ att) {
    __shared__ u16 Ks[2][128 * 64];   // [key][kd], 16B-chunk XOR swizzled
    __shared__ u16 Vt[2][64 * 128];   // [kd][key], 16B-chunk XOR swizzled

    const int tid = threadIdx.x;
    const int lane = tid & 63;
    const int w = tid >> 6;
    const int qd = lane >> 4;
    const int c = lane & 15;

    // XCD swizzle: flat%8 == bh%8 -> one bh's K/V stays in one XCD L2
    const int flat = blockIdx.x + 8 * blockIdx.y;
    const int bh = (flat & 7) + 8 * ((flat >> 3) & 7);
    const int bx = flat >> 6;                 // 0..7
    const int b = bh >> 4, h = bh & 15;

    const u16* Qg = qkv + (size_t)bh * 131072;
    const u16* Kg = qkv + (size_t)(64 + bh) * 131072;
    const u16* Vg = qkv + (size_t)(128 + bh) * 131072;   // [kd][2048]

    u32 kf_off[2];
#pragma unroll
    for (int ks = 0; ks < 2; ++ks)
        kf_off[ks] = c * 64 + (((ks * 4 + qd) ^ (c & 7)) << 3);
    u32 vf_off[4];
#pragma unroll
    for (int kc = 0; kc < 4; ++kc)
        vf_off[kc] = c * 128 + (((kc * 4 + qd) ^ c) << 3);

    // 8 x 16B async copies per tile (K and V), pre-swizzled global source,
    // linear LDS dest (global_load_lds requirement). Writes LDS only.
    auto issue_copy = [&](int t, u16* kd, u16* vd) {
#pragma unroll
        for (int it = 0; it < 4; ++it) {
            int lin = it * 256 + tid;
            int krw = lin >> 3, kch = lin & 7;
            int vrw = lin >> 4, vch = lin & 15;
            async_copy16(Kg + (size_t)t * 8192 + krw * 64 + ((kch ^ (krw & 7)) << 3),
                         kd + lin * 8);
            async_copy16(Vg + (size_t)t * 128 + (size_t)vrw * 2048 + ((vch ^ (vrw & 15)) << 3),
                         vd + lin * 8);
        }
    };

    const int qt0 = bx;                        // near tile (<= qt1 always)
    const int qt1 = 15 - bx;                   // far tile
    const int NT  = qt1 + 1;                   // staged tiles: 9..16

    const int qa0_row = qt0 * 128 + w * 32 + c;
    const int qb0_row = qa0_row + 16;
    const int qa1_row = qt1 * 128 + w * 32 + c;
    const int qb1_row = qa1_row + 16;

    bf16x8 qa0[2], qb0[2], qa1[2], qb1[2];
#pragma unroll
    for (int ks = 0; ks < 2; ++ks) {
        qa0[ks] = *(const bf16x8*)(Qg + (size_t)qa0_row * 64 + ks * 32 + qd * 8);
        qb0[ks] = *(const bf16x8*)(Qg + (size_t)qb0_row * 64 + ks * 32 + qd * 8);
        qa1[ks] = *(const bf16x8*)(Qg + (size_t)qa1_row * 64 + ks * 32 + qd * 8);
        qb1[ks] = *(const bf16x8*)(Qg + (size_t)qb1_row * 64 + ks * 32 + qd * 8);
    }

    f32x4 aa0[4] = {}, ab0[4] = {}, aa1[4] = {}, ab1[4] = {};
    f32x4 rva0 = {}, rvb0 = {}, rva1 = {}, rvb1 = {};
    f32x4 sa[8], sb[8];                        // ONE transient S set

    // ---- prologue: tile 0 staged; tile 1 issued ----
    issue_copy(0, Ks[0], Vt[0]);
    __syncthreads();                           // tile 0 landed (all waves)
    if (NT > 1) issue_copy(1, Ks[1], Vt[1]);

#pragma unroll 1
    for (int kt = 0; kt < NT; ++kt) {
        const int p = kt & 1;
        if (kt <= qt0) {                       // near segment shares this tile
            ATTN_S(Ks[p], qa0, qb0);
            ATTN_FIN(Vt[p], kt, qt0, qa0_row, qb0_row, rva0, rvb0, aa0, ab0);
        }
        ATTN_S(Ks[p], qa1, qb1);               // far segment, every tile
        ATTN_FIN(Vt[p], kt, qt1, qa1_row, qb1_row, rva1, rvb1, aa1, ab1);
        if (kt + 1 < NT) {
            __syncthreads();                   // tile kt+1 landed; buf p free
            if (kt + 2 < NT) issue_copy(kt + 2, Ks[p], Vt[p]);
        }
    }

    // epilogue: both segments
#pragma unroll
    for (int sgi = 0; sgi < 2; ++sgi) {
        f32x4* Aa = sgi ? aa1 : aa0;
        f32x4* Ab = sgi ? ab1 : ab0;
        f32x4 rv_a = sgi ? rva1 : rva0;
        f32x4 rv_b = sgi ? rvb1 : rvb0;
        int ra_row = sgi ? qa1_row : qa0_row;
        int rb_row = sgi ? qb1_row : qb0_row;
        float ra = rv_a[0] + rv_a[1] + rv_a[2] + rv_a[3];
        float rb = rv_b[0] + rv_b[1] + rv_b[2] + rv_b[3];
        ra += __shfl_xor(ra, 16, 64);
        ra += __shfl_xor(ra, 32, 64);
        rb += __shfl_xor(rb, 16, 64);
        rb += __shfl_xor(rb, 32, 64);
        float ia = __builtin_amdgcn_rcpf(ra), ib = __builtin_amdgcn_rcpf(rb);
        u16* ar = att + ((size_t)b * 2048 + ra_row) * 1024 + h * 64;
        u16* br = att + ((size_t)b * 2048 + rb_row) * 1024 + h * 64;
#pragma unroll
        for (int jo = 0; jo < 4; ++jo) {
            u32x2 oa, ob;
            oa[0] = pack_bf16(Aa[jo][0] * ia, Aa[jo][1] * ia);
            oa[1] = pack_bf16(Aa[jo][2] * ia, Aa[jo][3] * ia);
            ob[0] = pack_bf16(Ab[jo][0] * ib, Ab[jo][1] * ib);
            ob[1] = pack_bf16(Ab[jo][2] * ib, Ab[jo][3] * ib);
            *(u32x2*)(ar + jo * 16 + qd * 4) = oa;
            *(u32x2*)(br + jo * 16 + qd * 4) = ob;
        }
    }
}

// ---------------------------------------------------------------------------
extern "C" void kernel_launch(void* const* d_in, const int* in_sizes, int n_in,
                              void* d_out, int out_size, void* d_ws, size_t ws_size,
                              hipStream_t stream) {
    const float* x    = (const float*)d_in[0];   // [4,2048,1024]
    const float* Wqkv = (const float*)d_in[1];   // [1024,3072]
    const float* Wout = (const float*)d_in[2];   // [1024,1024]
    float* out = (float*)d_out;                  // [4,2048,1024] fp32

    char* ws = (char*)d_ws;
    u16* x_bf   = (u16*)(ws);                    // 16 MB
    u16* wqkv_t = (u16*)(ws + 16777216);         // 6 MB   [3072][1024]
    u16* wout_t = (u16*)(ws + 23068672);         // 2 MB   [1024][1024]
    u16* qkv_h  = (u16*)(ws + 25165824);         // 48 MB  Q,K [bh][l][64], V^T [bh][kd][2048]
    u16* att    = (u16*)(ws + 75497472);         // 16 MB  [4][2048][1024]

    prep<<<dim3(5120), dim3(256), 0, stream>>>(x, Wqkv, Wout, x_bf, wqkv_t, wout_t);
    gemm_qkv<<<dim3(1536), dim3(256), 0, stream>>>(x_bf, wqkv_t, qkv_h, 1024, 3072);
    attn_kernel<<<dim3(8, 64), dim3(256), 0, stream>>>(qkv_h, att);
    gemm_out<<<dim3(512), dim3(256), 0, stream>>>(att, wout_t, out, 1024, 1024);
}

// Round 10
// 235.636 us; speedup vs baseline: 2.9118x; 1.0146x over previous
//
#include <hip/hip_runtime.h>

typedef unsigned short u16;
typedef unsigned int   u32;
typedef __bf16   bf16x8 __attribute__((ext_vector_type(8)));
typedef float    f32x4  __attribute__((ext_vector_type(4)));
typedef u16      u16x4  __attribute__((ext_vector_type(4)));
typedef u16      u16x8  __attribute__((ext_vector_type(8)));
typedef u32      u32x2  __attribute__((ext_vector_type(2)));
typedef u32      u32x4  __attribute__((ext_vector_type(4)));

#if __has_builtin(__builtin_amdgcn_exp2f)
#define EXP2(x) __builtin_amdgcn_exp2f(x)
#else
#define EXP2(x) exp2f(x)
#endif

// fp32 -> bf16 round-to-nearest-even
__device__ __forceinline__ u16 f2bf(float f) {
    unsigned u = __float_as_uint(f);
    u += 0x7FFFu + ((u >> 16) & 1u);
    return (u16)(u >> 16);
}

__device__ __forceinline__ u32 pack_bf16(float a, float b) {
#if __has_builtin(__builtin_amdgcn_cvt_pk_bf16_f32)
    typedef __bf16 bf16x2 __attribute__((ext_vector_type(2)));
    bf16x2 r = __builtin_amdgcn_cvt_pk_bf16_f32(a, b);
    return __builtin_bit_cast(u32, r);
#else
    return (u32)f2bf(a) | ((u32)f2bf(b) << 16);
#endif
}

// async global->LDS, 16 bytes/lane. LDS dest = wave-uniform base + lane*16.
__device__ __forceinline__ void async_copy16(const u16* g, u16* l) {
    __builtin_amdgcn_global_load_lds(
        (const __attribute__((address_space(1))) unsigned*)g,
        (__attribute__((address_space(3))) unsigned*)l, 16, 0, 0);
}

__device__ __forceinline__ bf16x8 lds_frag(const u16* p) {
    return *(const bf16x8*)p;
}

// gfx950 cross-lane swaps (both operands read-write).
__device__ __forceinline__ void permlane32_swap(u32& a, u32& b) {
    asm("v_permlane32_swap_b32 %0, %1" : "+v"(a), "+v"(b));
}
__device__ __forceinline__ void permlane16_swap(u32& a, u32& b) {
    asm("v_permlane16_swap_b32 %0, %1" : "+v"(a), "+v"(b));
}

// ---------------------------------------------------------------------------
// Fused prep: blocks [0,768) transpose Wqkv, [768,1024) transpose Wout,
// [1024,5120) convert x to bf16 (16 elems/thread).
__global__ __launch_bounds__(256) void prep(const float* __restrict__ x,
                                            const float* __restrict__ Wqkv,
                                            const float* __restrict__ Wout,
                                            u16* __restrict__ xb,
                                            u16* __restrict__ wqkv_t,
                                            u16* __restrict__ wout_t) {
    __shared__ u16 t[64 * 72];
    const int bid = blockIdx.x;
    const int tid = threadIdx.x;

    if (bid >= 1024) {
        // x fp32 -> bf16
        size_t i = ((size_t)(bid - 1024) * 256 + tid) * 8;
        float4 v0 = *(const float4*)(x + i);
        float4 v1 = *(const float4*)(x + i + 4);
        u16x8 o = { f2bf(v0.x), f2bf(v0.y), f2bf(v0.z), f2bf(v0.w),
                    f2bf(v1.x), f2bf(v1.y), f2bf(v1.z), f2bf(v1.w) };
        *(u16x8*)(xb + i) = o;
        return;
    }

    // W fp32 [Kd][Nd] -> Wt bf16 [Nd][Kd]
    const float* W;  u16* Wt;  int Kd, Nd, n0, k0;
    if (bid < 768) { W = Wqkv; Wt = wqkv_t; Kd = 1024; Nd = 3072;
                     n0 = (bid % 48) * 64; k0 = (bid / 48) * 64; }
    else           { W = Wout; Wt = wout_t; Kd = 1024; Nd = 1024;
                     n0 = ((bid - 768) % 16) * 64; k0 = ((bid - 768) / 16) * 64; }
#pragma unroll
    for (int i = 0; i < 4; ++i) {
        int lin = i * 256 + tid;
        int kr = lin >> 4, nc = (lin & 15) << 2;
        float4 v = *(const float4*)(W + (size_t)(k0 + kr) * Nd + n0 + nc);
        u16x4 o = { f2bf(v.x), f2bf(v.y), f2bf(v.z), f2bf(v.w) };
        *(u16x4*)&t[kr * 72 + nc] = o;
    }
    __syncthreads();
#pragma unroll
    for (int i = 0; i < 2; ++i) {
        int lin = i * 256 + tid;
        int nr = lin >> 3, kc = (lin & 7) << 3;
        u16x8 o;
#pragma unroll
        for (int jj = 0; jj < 8; ++jj) o[jj] = t[(kc + jj) * 72 + nr];
        *(u16x8*)(Wt + (size_t)(n0 + nr) * Kd + k0 + kc) = o;
    }
}

// ---------------------------------------------------------------------------
// QKV gemm: C[M,N] = A[M,K] * Bt[N,K]^T, 128x128 tile, BK=32, double-buffered
// (one barrier/iter), LDS chunk-XOR swizzle (conflict-free). Proven structure
// (74 us, 690 TF). XCD/L2 region mapping (FETCH 71.8->41 MB verified).
// Do-not-retry list: (a) coarse 8-phase 256^2 port (R4: -27%); (b) attn
// tile-level 2-deep S pipeline (R1/R6: scratch spill); (c) BK>=64 here
// (m132: 64KB LDS cuts blocks/CU 5->2 when grid supplies 6/CU).
__global__ __launch_bounds__(256) void gemm_qkv(const u16* __restrict__ A,
                                                const u16* __restrict__ Bt,
                                                u16* __restrict__ outb,
                                                int K, int N) {
    __shared__ u16 As[2][128 * 32];
    __shared__ u16 Bs[2][128 * 32];
    const int tid = threadIdx.x;
    const int lane = tid & 63;
    const int wv = tid >> 6;
    const int wr = (wv >> 1) * 64;
    const int wc = (wv & 1) * 64;
    const int qd = lane >> 4;
    const int c  = lane & 15;

    // XCD/L2 region mapping (bijective over 1536 = 8 regions of 16x12 tiles)
    const int flat = blockIdx.x;
    const int r_ = flat & 7;
    const int q_ = flat >> 3;                 // 0..191
    const int m0 = ((r_ >> 1) * 16 + q_ / 12) * 128;
    const int n0 = ((r_ & 1) * 12 + q_ % 12) * 128;

    const int srow = tid >> 2;
    const int sg = ((tid & 3) ^ ((srow >> 1) & 3)) << 3;   // swizzled source chunk

    const u16* Ag0 = A  + (size_t)(m0 +      srow) * K + sg;
    const u16* Ag1 = A  + (size_t)(m0 + 64 + srow) * K + sg;
    const u16* Bg0 = Bt + (size_t)(n0 +      srow) * K + sg;
    const u16* Bg1 = Bt + (size_t)(n0 + 64 + srow) * K + sg;

    const u32 fsw = (qd ^ ((c >> 1) & 3)) << 3;            // swizzled frag chunk
    const u32 a_off = (wr + c) * 32 + fsw;                 // + i*512
    const u32 b_off = (wc + c) * 32 + fsw;                 // + j*512

    f32x4 acc[4][4] = {};

    async_copy16(Ag0, &As[0][tid * 8]);
    async_copy16(Ag1, &As[0][2048 + tid * 8]);
    async_copy16(Bg0, &Bs[0][tid * 8]);
    async_copy16(Bg1, &Bs[0][2048 + tid * 8]);

    int p = 0;
    for (int k0 = 0; k0 < K; k0 += 32) {
        __syncthreads();
        if (k0 + 32 < K) {
            const int np = p ^ 1;
            async_copy16(Ag0 + k0 + 32, &As[np][tid * 8]);
            async_copy16(Ag1 + k0 + 32, &As[np][2048 + tid * 8]);
            async_copy16(Bg0 + k0 + 32, &Bs[np][tid * 8]);
            async_copy16(Bg1 + k0 + 32, &Bs[np][2048 + tid * 8]);
        }
        bf16x8 af[4], bfr[4];
#pragma unroll
        for (int i = 0; i < 4; ++i) af[i]  = lds_frag(&As[p][a_off + i * 512]);
#pragma unroll
        for (int j = 0; j < 4; ++j) bfr[j] = lds_frag(&Bs[p][b_off + j * 512]);
#pragma unroll
        for (int i = 0; i < 4; ++i)
#pragma unroll
            for (int j = 0; j < 4; ++j)
                acc[i][j] = __builtin_amdgcn_mfma_f32_16x16x32_bf16(af[i], bfr[j], acc[i][j], 0, 0, 0);
        p ^= 1;
    }

    // C/D layout: col = lane&15, row = (lane>>4)*4 + reg
#pragma unroll
    for (int i = 0; i < 4; ++i)
#pragma unroll
        for (int j = 0; j < 4; ++j) {
            int n = n0 + wc + j * 16 + c;
            int which = n >> 10, h = (n >> 6) & 15, kd = n & 63;
            int m_base = m0 + wr + i * 16 + qd * 4;
            int b = m_base >> 11, l0 = m_base & 2047;
            int bh = b * 16 + h;
            if (which == 2) {
                u32x2 o2;
                o2[0] = pack_bf16(acc[i][j][0], acc[i][j][1]);
                o2[1] = pack_bf16(acc[i][j][2], acc[i][j][3]);
                *(u32x2*)(outb + (size_t)(128 + bh) * 131072 + (size_t)kd * 2048 + l0) = o2;
            } else if (which == 0) {
#pragma unroll
                for (int r = 0; r < 4; ++r)
                    outb[(size_t)bh * 131072 + (size_t)(l0 + r) * 64 + kd] =
                        f2bf(acc[i][j][r] * 0.1803368801f);   // 0.125*log2(e)
            } else {
#pragma unroll
                for (int r = 0; r < 4; ++r)
                    outb[(size_t)(64 + bh) * 131072 + (size_t)(l0 + r) * 64 + kd] =
                        f2bf(acc[i][j][r]);
            }
        }
}

// ---------------------------------------------------------------------------
// Output gemm, round-10: 128x128 tile, BK=64 (32 MFMA per barrier-pair,
// barrier count 32 -> 16). Safe here ONLY: grid 512 = exactly 2 blocks/CU,
// so the 64 KB LDS cap (=2 blocks) costs nothing (m132's regression
// mechanism -- LDS capping residency below grid supply -- cannot apply).
// [128 rows][64 u16] chunk-XOR layout identical to attn's proven
// conflict-free Ks geometry. fp32 epilogue. XCD regioning unchanged.
__global__ __launch_bounds__(256) void gemm_out(const u16* __restrict__ A,
                                                const u16* __restrict__ Bt,
                                                float* __restrict__ outf,
                                                int K, int N) {
    __shared__ u16 As[2][128 * 64];   // 16 KB per slot
    __shared__ u16 Bs[2][128 * 64];   // total 64 KB
    const int tid = threadIdx.x;
    const int lane = tid & 63;
    const int wv = tid >> 6;
    const int wr = (wv >> 1) * 64;
    const int wc = (wv & 1) * 64;
    const int qd = lane >> 4;
    const int c  = lane & 15;

    // bijective over 512 = 8 regions x (8 mtiles x 8 ntiles)
    const int flat = blockIdx.x;
    const int r_ = flat & 7;
    const int q_ = flat >> 3;                 // 0..63
    const int m0 = (r_ * 8 + (q_ >> 3)) * 128;
    const int n0 = (q_ & 7) * 128;

    // stage one BK=64 tile pair (A 16KB + B 16KB): 8 copies/thread.
    // dest linear in lin (global_load_lds requirement); source pre-swizzled
    // with the same ch ^ (row&7) involution the fragment reads use.
    auto stage = [&](int t, int slot) {
        const int kb = t * 64;
#pragma unroll
        for (int it = 0; it < 4; ++it) {
            int lin = it * 256 + tid;          // 0..1023
            int row = lin >> 3;                // 0..127
            int sch = ((lin & 7) ^ (row & 7)) << 3;
            async_copy16(A  + (size_t)(m0 + row) * K + kb + sch,
                         &As[slot][lin * 8]);
            async_copy16(Bt + (size_t)(n0 + row) * K + kb + sch,
                         &Bs[slot][lin * 8]);
        }
    };

    // fragment offsets: row stride 64 u16; frag row = (wr|wc) + c + {i,j}*16;
    // (row&7) == (c&7) for all i,j since wr/wc/i*16 are multiples of 8.
    const u32 a_base = (wr + c) * 64;          // + i*1024
    const u32 b_base = (wc + c) * 64;          // + j*1024
    const u32 ch0 = (u32)((qd ^ (c & 7)) << 3);        // ks=0 chunk
    const u32 ch1 = (u32)(((4 + qd) ^ (c & 7)) << 3);  // ks=1 chunk

    f32x4 acc[4][4] = {};

    stage(0, 0);

    const int NT = K >> 6;   // 16
    int p = 0;
#pragma unroll 1
    for (int kt = 0; kt < NT; ++kt) {
        __syncthreads();                       // tile p landed; buf p^1 free
        if (kt + 1 < NT) stage(kt + 1, p ^ 1);

        bf16x8 af[4], bfr[4];
        // ks = 0
#pragma unroll
        for (int i = 0; i < 4; ++i) af[i]  = lds_frag(&As[p][a_base + i * 1024 + ch0]);
#pragma unroll
        for (int j = 0; j < 4; ++j) bfr[j] = lds_frag(&Bs[p][b_base + j * 1024 + ch0]);
#pragma unroll
        for (int i = 0; i < 4; ++i)
#pragma unroll
            for (int j = 0; j < 4; ++j)
                acc[i][j] = __builtin_amdgcn_mfma_f32_16x16x32_bf16(af[i], bfr[j], acc[i][j], 0, 0, 0);
        // ks = 1
#pragma unroll
        for (int i = 0; i < 4; ++i) af[i]  = lds_frag(&As[p][a_base + i * 1024 + ch1]);
#pragma unroll
        for (int j = 0; j < 4; ++j) bfr[j] = lds_frag(&Bs[p][b_base + j * 1024 + ch1]);
#pragma unroll
        for (int i = 0; i < 4; ++i)
#pragma unroll
            for (int j = 0; j < 4; ++j)
                acc[i][j] = __builtin_amdgcn_mfma_f32_16x16x32_bf16(af[i], bfr[j], acc[i][j], 0, 0, 0);
        p ^= 1;
    }

    // C/D layout: col = lane&15, row = (lane>>4)*4 + reg
#pragma unroll
    for (int i = 0; i < 4; ++i)
#pragma unroll
        for (int j = 0; j < 4; ++j) {
            int n = n0 + wc + j * 16 + c;
            int m_base = m0 + wr + i * 16 + qd * 4;
#pragma unroll
            for (int r = 0; r < 4; ++r)
                outf[(size_t)(m_base + r) * N + n] = acc[i][j][r];
        }
}

// ---------------------------------------------------------------------------
// Flash attention, causal, S^T form (R9 merged-segment version, verified).
// Each block owns Q-tiles qt0=bx and qt1=15-bx; one loop over kt stages each
// K/V tile once, both segments consume it. Fused a/b streams (shared K and V
// fragment reads), in-register P^T via permlane swaps, exp2 bias -8 folded
// into MFMA C-init, packed f32x4 row-sums, setprio on MFMA clusters,
// K/V double-buffered (64 KB -> 2 blocks/CU), one barrier/tile.
#define ATTN_S(KSB, QA, QB)                                                   \
    do {                                                                      \
        _Pragma("unroll") for (int f = 0; f < 8; ++f) {                       \
            sa[f] = f32x4{-8.f, -8.f, -8.f, -8.f};                            \
            sb[f] = f32x4{-8.f, -8.f, -8.f, -8.f};                            \
        }                                                                     \
        __builtin_amdgcn_s_setprio(1);                                        \
        _Pragma("unroll") for (int ks = 0; ks < 2; ++ks) {                    \
            const u16* kp = (KSB) + kf_off[ks];                               \
            _Pragma("unroll") for (int f = 0; f < 8; ++f) {                   \
                bf16x8 kf = lds_frag(kp + f * 1024);                          \
                sa[f] = __builtin_amdgcn_mfma_f32_16x16x32_bf16(              \
                    kf, QA[ks], sa[f], 0, 0, 0);                              \
                sb[f] = __builtin_amdgcn_mfma_f32_16x16x32_bf16(              \
                    kf, QB[ks], sb[f], 0, 0, 0);                              \
            }                                                                 \
        }                                                                     \
        __builtin_amdgcn_s_setprio(0);                                        \
    } while (0)

#define ATTN_FIN(VTB, KT, QT, QAROW, QBROW, RVA, RVB, ACCA, ACCB)             \
    do {                                                                      \
        if ((KT) == (QT)) {                                                   \
            _Pragma("unroll") for (int f = 0; f < 8; ++f)                     \
                _Pragma("unroll") for (int r = 0; r < 4; ++r) {               \
                    int key = (KT) * 128 + f * 16 + qd * 4 + r;               \
                    if (key > (QAROW)) sa[f][r] = -3e38f;                     \
                    if (key > (QBROW)) sb[f][r] = -3e38f;                     \
                }                                                             \
        }                                                                     \
        _Pragma("unroll") for (int f = 0; f < 8; ++f) {                       \
            _Pragma("unroll") for (int r = 0; r < 4; ++r) {                   \
                sa[f][r] = EXP2(sa[f][r]);                                    \
                sb[f][r] = EXP2(sb[f][r]);                                    \
            }                                                                 \
            RVA += sa[f];                                                     \
            RVB += sb[f];                                                     \
        }                                                                     \
        _Pragma("unroll") for (int kc = 0; kc < 4; ++kc) {                    \
            u32 a0 = pack_bf16(sa[2 * kc][0], sa[2 * kc][1]);                 \
            u32 a1 = pack_bf16(sa[2 * kc + 1][0], sa[2 * kc + 1][1]);         \
            u32 b0 = pack_bf16(sa[2 * kc][2], sa[2 * kc][3]);                 \
            u32 b1 = pack_bf16(sa[2 * kc + 1][2], sa[2 * kc + 1][3]);         \
            permlane32_swap(a0, a1); permlane16_swap(a0, a1);                 \
            permlane32_swap(b0, b1); permlane16_swap(b0, b1);                 \
            u32x4 wpa = {a0, b0, a1, b1};                                     \
            bf16x8 pa = __builtin_bit_cast(bf16x8, wpa);                      \
            u32 c0 = pack_bf16(sb[2 * kc][0], sb[2 * kc][1]);                 \
            u32 c1 = pack_bf16(sb[2 * kc + 1][0], sb[2 * kc + 1][1]);         \
            u32 d0 = pack_bf16(sb[2 * kc][2], sb[2 * kc][3]);                 \
            u32 d1 = pack_bf16(sb[2 * kc + 1][2], sb[2 * kc + 1][3]);         \
            permlane32_swap(c0, c1); permlane16_swap(c0, c1);                 \
            permlane32_swap(d0, d1); permlane16_swap(d0, d1);                 \
            u32x4 wpb = {c0, d0, c1, d1};                                     \
            bf16x8 pb = __builtin_bit_cast(bf16x8, wpb);                      \
            const u16* vp = (VTB) + vf_off[kc];                               \
            __builtin_amdgcn_s_setprio(1);                                    \
            _Pragma("unroll") for (int jo = 0; jo < 4; ++jo) {                \
                bf16x8 vf = lds_frag(vp + jo * 2048);                         \
                ACCA[jo] = __builtin_amdgcn_mfma_f32_16x16x32_bf16(           \
                    vf, pa, ACCA[jo], 0, 0, 0);                               \
                ACCB[jo] = __builtin_amdgcn_mfma_f32_16x16x32_bf16(           \
                    vf, pb, ACCB[jo], 0, 0, 0);                               \
            }                                                                 \
            __builtin_amdgcn_s_setprio(0);                                    \
        }                                                                     \
    } while (0)

__global__ __launch_bounds__(256, 2) void attn_kernel(const u16* __restrict__ qkv,
                                                      u16* __restrict__ att) {
    __shared__ u16 Ks[2][128 * 64];   // [key][kd], 16B-chunk XOR swizzled
    __shared__ u16 Vt[2][64 * 128];   // [kd][key], 16B-chunk XOR swizzled

    const int tid = threadIdx.x;
    const int lane = tid & 63;
    const int w = tid >> 6;
    const int qd = lane >> 4;
    const int c = lane & 15;

    // XCD swizzle: flat%8 == bh%8 -> one bh's K/V stays in one XCD L2
    const int flat = blockIdx.x + 8 * blockIdx.y;
    const int bh = (flat & 7) + 8 * ((flat >> 3) & 7);
    const int bx = flat >> 6;                 // 0..7
    const int b = bh >> 4, h = bh & 15;

    const u16* Qg = qkv + (size_t)bh * 131072;
    const u16* Kg = qkv + (size_t)(64 + bh) * 131072;
    const u16* Vg = qkv + (size_t)(128 + bh) * 131072;   // [kd][2048]

    u32 kf_off[2];
#pragma unroll
    for (int ks = 0; ks < 2; ++ks)
        kf_off[ks] = c * 64 + (((ks * 4 + qd) ^ (c & 7)) << 3);
    u32 vf_off[4];
#pragma unroll
    for (int kc = 0; kc < 4; ++kc)
        vf_off[kc] = c * 128 + (((kc * 4 + qd) ^ c) << 3);

    // 8 x 16B async copies per tile (K and V), pre-swizzled global source,
    // linear LDS dest (global_load_lds requirement). Writes LDS only.
    auto issue_copy = [&](int t, u16* kd, u16* vd) {
#pragma unroll
        for (int it = 0; it < 4; ++it) {
            int lin = it * 256 + tid;
            int krw = lin >> 3, kch = lin & 7;
            int vrw = lin >> 4, vch = lin & 15;
            async_copy16(Kg + (size_t)t * 8192 + krw * 64 + ((kch ^ (krw & 7)) << 3),
                         kd + lin * 8);
            async_copy16(Vg + (size_t)t * 128 + (size_t)vrw * 2048 + ((vch ^ (vrw & 15)) << 3),
                         vd + lin * 8);
        }
    };

    const int qt0 = bx;                        // near tile (<= qt1 always)
    const int qt1 = 15 - bx;                   // far tile
    const int NT  = qt1 + 1;                   // staged tiles: 9..16

    const int qa0_row = qt0 * 128 + w * 32 + c;
    const int qb0_row = qa0_row + 16;
    const int qa1_row = qt1 * 128 + w * 32 + c;
    const int qb1_row = qa1_row + 16;

    bf16x8 qa0[2], qb0[2], qa1[2], qb1[2];
#pragma unroll
    for (int ks = 0; ks < 2; ++ks) {
        qa0[ks] = *(const bf16x8*)(Qg + (size_t)qa0_row * 64 + ks * 32 + qd * 8);
        qb0[ks] = *(const bf16x8*)(Qg + (size_t)qb0_row * 64 + ks * 32 + qd * 8);
        qa1[ks] = *(const bf16x8*)(Qg + (size_t)qa1_row * 64 + ks * 32 + qd * 8);
        qb1[ks] = *(const bf16x8*)(Qg + (size_t)qb1_row * 64 + ks * 32 + qd * 8);
    }

    f32x4 aa0[4] = {}, ab0[4] = {}, aa1[4] = {}, ab1[4] = {};
    f32x4 rva0 = {}, rvb0 = {}, rva1 = {}, rvb1 = {};
    f32x4 sa[8], sb[8];                        // ONE transient S set

    // ---- prologue: tile 0 staged; tile 1 issued ----
    issue_copy(0, Ks[0], Vt[0]);
    __syncthreads();                           // tile 0 landed (all waves)
    if (NT > 1) issue_copy(1, Ks[1], Vt[1]);

#pragma unroll 1
    for (int kt = 0; kt < NT; ++kt) {
        const int p = kt & 1;
        if (kt <= qt0) {                       // near segment shares this tile
            ATTN_S(Ks[p], qa0, qb0);
            ATTN_FIN(Vt[p], kt, qt0, qa0_row, qb0_row, rva0, rvb0, aa0, ab0);
        }
        ATTN_S(Ks[p], qa1, qb1);               // far segment, every tile
        ATTN_FIN(Vt[p], kt, qt1, qa1_row, qb1_row, rva1, rvb1, aa1, ab1);
        if (kt + 1 < NT) {
            __syncthreads();                   // tile kt+1 landed; buf p free
            if (kt + 2 < NT) issue_copy(kt + 2, Ks[p], Vt[p]);
        }
    }

    // epilogue: both segments
#pragma unroll
    for (int sgi = 0; sgi < 2; ++sgi) {
        f32x4* Aa = sgi ? aa1 : aa0;
        f32x4* Ab = sgi ? ab1 : ab0;
        f32x4 rv_a = sgi ? rva1 : rva0;
        f32x4 rv_b = sgi ? rvb1 : rvb0;
        int ra_row = sgi ? qa1_row : qa0_row;
        int rb_row = sgi ? qb1_row : qb0_row;
        float ra = rv_a[0] + rv_a[1] + rv_a[2] + rv_a[3];
        float rb = rv_b[0] + rv_b[1] + rv_b[2] + rv_b[3];
        ra += __shfl_xor(ra, 16, 64);
        ra += __shfl_xor(ra, 32, 64);
        rb += __shfl_xor(rb, 16, 64);
        rb += __shfl_xor(rb, 32, 64);
        float ia = __builtin_amdgcn_rcpf(ra), ib = __builtin_amdgcn_rcpf(rb);
        u16* ar = att + ((size_t)b * 2048 + ra_row) * 1024 + h * 64;
        u16* br = att + ((size_t)b * 2048 + rb_row) * 1024 + h * 64;
#pragma unroll
        for (int jo = 0; jo < 4; ++jo) {
            u32x2 oa, ob;
            oa[0] = pack_bf16(Aa[jo][0] * ia, Aa[jo][1] * ia);
            oa[1] = pack_bf16(Aa[jo][2] * ia, Aa[jo][3] * ia);
            ob[0] = pack_bf16(Ab[jo][0] * ib, Ab[jo][1] * ib);
            ob[1] = pack_bf16(Ab[jo][2] * ib, Ab[jo][3] * ib);
            *(u32x2*)(ar + jo * 16 + qd * 4) = oa;
            *(u32x2*)(br + jo * 16 + qd * 4) = ob;
        }
    }
}

// ---------------------------------------------------------------------------
extern "C" void kernel_launch(void* const* d_in, const int* in_sizes, int n_in,
                              void* d_out, int out_size, void* d_ws, size_t ws_size,
                              hipStream_t stream) {
    const float* x    = (const float*)d_in[0];   // [4,2048,1024]
    const float* Wqkv = (const float*)d_in[1];   // [1024,3072]
    const float* Wout = (const float*)d_in[2];   // [1024,1024]
    float* out = (float*)d_out;                  // [4,2048,1024] fp32

    char* ws = (char*)d_ws;
    u16* x_bf   = (u16*)(ws);                    // 16 MB
    u16* wqkv_t = (u16*)(ws + 16777216);         // 6 MB   [3072][1024]
    u16* wout_t = (u16*)(ws + 23068672);         // 2 MB   [1024][1024]
    u16* qkv_h  = (u16*)(ws + 25165824);         // 48 MB  Q,K [bh][l][64], V^T [bh][kd][2048]
    u16* att    = (u16*)(ws + 75497472);         // 16 MB  [4][2048][1024]

    prep<<<dim3(5120), dim3(256), 0, stream>>>(x, Wqkv, Wout, x_bf, wqkv_t, wout_t);
    gemm_qkv<<<dim3(1536), dim3(256), 0, stream>>>(x_bf, wqkv_t, qkv_h, 1024, 3072);
    attn_kernel<<<dim3(8, 64), dim3(256), 0, stream>>>(qkv_h, att);
    gemm_out<<<dim3(512), dim3(256), 0, stream>>>(att, wout_t, out, 1024, 1024);
}